// Round 2
// 554.711 us; speedup vs baseline: 1.0413x; 1.0413x over previous
//
#include <hip/hip_runtime.h>
#include <hip/hip_bf16.h>
#include <stdint.h>

// ---------------- problem constants (from setup_inputs) ----------------
constexpr int Mrows = 8192;   // B*S
constexpr int Hdim  = 2048;   // K of main GEMM
constexpr int Sdim  = 4096;
constexpr int HnD   = 4096;   // Hn*D
constexpr int Hn    = 32;
constexpr int Dd    = 128;
constexpr int Lc    = 16384;
constexpr int NFULL = 4352;   // 4096 q + 128 k + 32 w + 96 zero pad (34 tiles of 128)

typedef unsigned short u16;
typedef __attribute__((ext_vector_type(8))) short    bf16x8;
typedef __attribute__((ext_vector_type(4))) float    f32x4;
typedef __attribute__((ext_vector_type(8))) unsigned short u16x8;

__device__ __forceinline__ float bf2f(u16 u) {
    union { unsigned int i; float f; } v; v.i = ((unsigned int)u) << 16; return v.f;
}
__device__ __forceinline__ u16 f2bf(float f) {
    union { float f; unsigned int i; } v; v.f = f;
    unsigned int x = v.i;
    return (u16)((x + 0x7fffu + ((x >> 16) & 1u)) >> 16);   // RNE
}
__device__ __forceinline__ void gload_lds16(const void* g, void* l) {
    __builtin_amdgcn_global_load_lds(
        (const __attribute__((address_space(1))) void*)g,
        (__attribute__((address_space(3))) void*)l, 16, 0, 0);
}

// ------- 1) per-row stats (rms, mu, rstd) + fp32 -> bf16 copy of x -------
__global__ __launch_bounds__(256) void stats_cvt(
    const float* __restrict__ x, u16* __restrict__ xb, float* __restrict__ rms,
    float* __restrict__ mu, float* __restrict__ rstd)
{
    int r = blockIdx.x, t = threadIdx.x;
    const float4* xr = (const float4*)(x + (size_t)r * Hdim);
    float4 a = xr[2 * t], bq = xr[2 * t + 1];
    float v[8] = {a.x, a.y, a.z, a.w, bq.x, bq.y, bq.z, bq.w};
    float s = 0.f, ss = 0.f;
    __align__(16) u16 o[8];
    #pragma unroll
    for (int i = 0; i < 8; i++) { s += v[i]; ss += v[i] * v[i]; o[i] = f2bf(v[i]); }
    ((u16x8*)(xb + (size_t)r * Hdim))[t] = *(const u16x8*)o;
    for (int oo = 32; oo > 0; oo >>= 1) { s += __shfl_down(s, oo); ss += __shfl_down(ss, oo); }
    __shared__ float as[4], ass[4];
    if ((t & 63) == 0) { as[t >> 6] = s; ass[t >> 6] = ss; }
    __syncthreads();
    if (t == 0) {
        float S1 = as[0] + as[1] + as[2] + as[3];
        float S2 = ass[0] + ass[1] + ass[2] + ass[3];
        float mean = S1 / Hdim, msq = S2 / Hdim;
        rms[r]  = rsqrtf(msq + 1e-6f);
        mu[r]   = mean;
        rstd[r] = rsqrtf(msq - mean * mean + 1e-6f);
    }
}

// ---------------- 2) build B'^T = [c1*wqb | g*wk | wproj | 0]^T, [NFULL][H] ---
__global__ __launch_bounds__(256) void prep_wt(
    const float* __restrict__ wqb, const float* __restrict__ qn, const float* __restrict__ qns,
    const float* __restrict__ wk,  const float* __restrict__ g,  const float* __restrict__ wproj,
    u16* __restrict__ wt)
{
    __shared__ u16 tile[64][72];
    int k0 = blockIdx.x * 64, n0 = blockIdx.y * 64;
    int t = threadIdx.x;
    int lk = t >> 2, lc0 = (t & 3) * 16;
    int k = k0 + lk;
    float c1k = qn[k] * qns[k];
    float gk  = g[k];
    #pragma unroll
    for (int i = 0; i < 16; i++) {
        int n = n0 + lc0 + i;
        float val;
        if (n < 4096)      val = wqb[(size_t)k * HnD + n] * c1k;
        else if (n < 4224) val = wk[k * Dd + (n - 4096)] * gk;
        else if (n < 4256) val = wproj[k * Hn + (n - 4224)];
        else               val = 0.f;
        tile[lk][lc0 + i] = f2bf(val);
    }
    __syncthreads();
    int ln = t >> 2, lk0 = (t & 3) * 16;
    __align__(16) u16 o[16];
    #pragma unroll
    for (int i = 0; i < 16; i++) o[i] = tile[lk0 + i][ln];
    u16* dst = wt + (size_t)(n0 + ln) * Hdim + k0 + lk0;
    *(u16x8*)dst = *(const u16x8*)o;
    *(u16x8*)(dst + 8) = *((const u16x8*)o + 1);
}

// ------- 3) transpose hadamard matrices to bf16 (LDS-tiled, coalesced) ----
__global__ __launch_bounds__(256) void transpose_h(
    const float* __restrict__ hq, const float* __restrict__ hk,
    u16* __restrict__ hqt, u16* __restrict__ hkt)
{
    __shared__ float tile[128][129];
    const float* src = blockIdx.x ? hk : hq;
    u16* dst = blockIdx.x ? hkt : hqt;
    int t = threadIdx.x;
    int r = t >> 1, h = (t & 1) * 64;
    #pragma unroll
    for (int j = 0; j < 16; j++) {
        float4 v = *(const float4*)(src + r * Dd + h + 4 * j);
        tile[r][h + 4 * j]     = v.x;
        tile[r][h + 4 * j + 1] = v.y;
        tile[r][h + 4 * j + 2] = v.z;
        tile[r][h + 4 * j + 3] = v.w;
    }
    __syncthreads();
    #pragma unroll
    for (int j0 = 0; j0 < 64; j0 += 8) {
        __align__(16) u16 o[8];
        #pragma unroll
        for (int j = 0; j < 8; j++) o[j] = f2bf(tile[h + j0 + j][r]);
        *(u16x8*)(dst + r * Dd + h + j0) = *(const u16x8*)o;
    }
}

// ---------------- 4) bdot[n]=sum_k b*wk, gdot[n]=sum_k g*wk ------------
__global__ __launch_bounds__(256) void bg_dot(
    const float* __restrict__ wk, const float* __restrict__ g, const float* __restrict__ b,
    float* __restrict__ bdot, float* __restrict__ gdot)
{
    int n = blockIdx.x, t = threadIdx.x;
    float sb = 0.f, sg = 0.f;
    for (int k = t; k < Hdim; k += 256) {
        float w = wk[k * Dd + n];
        sb += b[k] * w;
        sg += g[k] * w;
    }
    for (int o = 32; o > 0; o >>= 1) { sb += __shfl_down(sb, o); sg += __shfl_down(sg, o); }
    __shared__ float rb[4], rg[4];
    if ((t & 63) == 0) { rb[t >> 6] = sb; rg[t >> 6] = sg; }
    __syncthreads();
    if (t == 0) { bdot[n] = rb[0] + rb[1] + rb[2] + rb[3]; gdot[n] = rg[0] + rg[1] + rg[2] + rg[3]; }
}

// ---------------- 5) main fused GEMM: C = xb @ B', fully fused q epilogue ----
// Wave mapping: each wave owns 32 rows x 128 cols (acc[2][8]) so the RoPE
// rotate-half partner (d <-> d^64) is acc[mt][nt^4][reg] — in-register.
// For bn<32 the epilogue does rms*qbs scaling -> RoPE (fp32) -> bf16 P tile in
// LDS (layout transpose) -> MFMA vs hadamard^T (global, L2-hot) -> absmax ->
// quant -> final store. Eliminates the qpre HBM round trip + post_kernel<0>.
__global__ __launch_bounds__(256) void main_gemm(
    const u16* __restrict__ A, const u16* __restrict__ Bt,
    const float* __restrict__ rms, const float* __restrict__ mu, const float* __restrict__ rstd,
    const float* __restrict__ qbs,        // w_qb_scale [4096] fp32
    const float* __restrict__ bdot, const float* __restrict__ gdot,
    const u16* __restrict__ hqt,          // transposed hadamard_q [e][d] bf16
    const float* __restrict__ cosr, const float* __restrict__ sinr,  // [S][128] fp32
    float* __restrict__ oq,               // [M][4096] final q (fp32 ints)
    float* __restrict__ oqs,              // [M][32] q scales
    float* __restrict__ kpre,             // [M][128] fp32 ws
    float* __restrict__ wout)             // [M][32] fp32 weights output
{
    constexpr int BK = 32;
    constexpr int PB = 272;               // P-tile row stride in BYTES (16B-aligned)
    // union: main loop uses first 16 KB as smA|smB; epilogue reuses all 34 KB as P
    __shared__ __align__(16) char lds[128 * PB];   // 34816 B
    u16* smA = (u16*)lds;                 // [128][32] bf16, 8192 B
    u16* smB = (u16*)(lds + 8192);        // [128][32] bf16, 8192 B

    int bm = blockIdx.x, bn = blockIdx.y;
    int tid = threadIdx.x, w = tid >> 6, lane = tid & 63;
    int quad = lane >> 4, l15 = lane & 15;
    int brow = bm * 128;

    f32x4 acc[2][8] = {};

    // staging: per wave 32 rows of A and 32 of B, 16B per lane (unchanged)
    const int srow = w * 32 + (lane >> 2);   // +c*16
    const int kch  = (lane & 3) * 8;
    const u16* Ab = A  + (size_t)brow * Hdim;
    const u16* Bb = Bt + (size_t)(bn * 128) * Hdim;

    for (int k0 = 0; k0 < Hdim; k0 += BK) {
        __syncthreads();
        #pragma unroll
        for (int c = 0; c < 2; c++) {
            int r = srow + c * 16;
            gload_lds16(Ab + (size_t)r * Hdim + k0 + kch, smA + (w * 32 + c * 16) * BK);
            gload_lds16(Bb + (size_t)r * Hdim + k0 + kch, smB + (w * 32 + c * 16) * BK);
        }
        __syncthreads();
        bf16x8 af[2], bfq[8];
        #pragma unroll
        for (int mt = 0; mt < 2; mt++)
            af[mt] = *(const bf16x8*)(smA + (w * 32 + mt * 16 + l15) * BK + quad * 8);
        #pragma unroll
        for (int nt = 0; nt < 8; nt++)
            bfq[nt] = *(const bf16x8*)(smB + (nt * 16 + l15) * BK + quad * 8);
        #pragma unroll
        for (int mt = 0; mt < 2; mt++)
            #pragma unroll
            for (int nt = 0; nt < 8; nt++)
                acc[mt][nt] = __builtin_amdgcn_mfma_f32_16x16x32_bf16(af[mt], bfq[nt], acc[mt][nt], 0, 0, 0);
    }

    if (bn < 32) {
        // -------- fused q epilogue: scale -> RoPE -> P(LDS) -> hadamard -> quant
        __syncthreads();   // everyone done reading smA/smB (aliased by P)
        float qb[8];
        #pragma unroll
        for (int nt = 0; nt < 8; nt++) qb[nt] = qbs[bn * 128 + nt * 16 + l15];
        #pragma unroll
        for (int mt = 0; mt < 2; mt++) {
            float y[8][4];
            #pragma unroll
            for (int reg = 0; reg < 4; reg++) {
                float rv = rms[brow + w * 32 + mt * 16 + quad * 4 + reg];
                #pragma unroll
                for (int nt = 0; nt < 8; nt++) y[nt][reg] = acc[mt][nt][reg] * rv * qb[nt];
            }
            #pragma unroll
            for (int reg = 0; reg < 4; reg++) {
                int rl = w * 32 + mt * 16 + quad * 4 + reg;
                int s_ = (brow + rl) & (Sdim - 1);
                const float* cr = cosr + (size_t)s_ * Dd + l15;
                const float* sr = sinr + (size_t)s_ * Dd + l15;
                u16* prow = (u16*)(lds + rl * PB);
                #pragma unroll
                for (int nt = 0; nt < 8; nt++) {
                    float c  = cr[nt * 16];
                    float sv = sr[nt * 16];
                    float sign = (nt < 4) ? -1.f : 1.f;
                    float o = y[nt][reg] * c + sign * y[nt ^ 4][reg] * sv;   // fp32 RoPE
                    prow[nt * 16 + l15] = f2bf(o);
                }
            }
        }
        __syncthreads();
        // hadamard: out[r][e] = sum_d P[r][d] * hq[d][e]  (B-operand hqt[e][d] from global)
        f32x4 a2[2][8] = {};
        #pragma unroll
        for (int kb = 0; kb < 4; kb++) {
            bf16x8 pa[2];
            #pragma unroll
            for (int mt = 0; mt < 2; mt++)
                pa[mt] = *(const bf16x8*)(lds + (w * 32 + mt * 16 + l15) * PB + kb * 64 + quad * 16);
            #pragma unroll
            for (int nt = 0; nt < 8; nt++) {
                bf16x8 hb = *(const bf16x8*)(hqt + (size_t)(nt * 16 + l15) * Dd + kb * 32 + quad * 8);
                #pragma unroll
                for (int mt = 0; mt < 2; mt++)
                    a2[mt][nt] = __builtin_amdgcn_mfma_f32_16x16x32_bf16(pa[mt], hb, a2[mt][nt], 0, 0, 0);
            }
        }
        // absmax per row (all 128 cols in-wave) -> quant -> store
        #pragma unroll
        for (int mt = 0; mt < 2; mt++)
            #pragma unroll
            for (int reg = 0; reg < 4; reg++) {
                float m = 0.f;
                #pragma unroll
                for (int nt = 0; nt < 8; nt++) m = fmaxf(m, fabsf(a2[mt][nt][reg]));
                m = fmaxf(m, __shfl_xor(m, 8));
                m = fmaxf(m, __shfl_xor(m, 4));
                m = fmaxf(m, __shfl_xor(m, 2));
                m = fmaxf(m, __shfl_xor(m, 1));
                float scale = fmaxf(m * (1.f / 127.f), 1e-8f);
                float inv = 1.f / scale;
                int r = brow + w * 32 + mt * 16 + quad * 4 + reg;
                float* orow = oq + (size_t)r * HnD + bn * 128;
                #pragma unroll
                for (int nt = 0; nt < 8; nt++)
                    orow[nt * 16 + l15] = rintf(a2[mt][nt][reg] * inv);
                if (l15 == 0) oqs[(size_t)r * Hn + bn] = scale;
            }
    } else if (bn == 32) {
        float bd[8], gd[8];
        #pragma unroll
        for (int nt = 0; nt < 8; nt++) { bd[nt] = bdot[nt * 16 + l15]; gd[nt] = gdot[nt * 16 + l15]; }
        #pragma unroll
        for (int mt = 0; mt < 2; mt++)
            #pragma unroll
            for (int reg = 0; reg < 4; reg++) {
                int r = brow + w * 32 + mt * 16 + quad * 4 + reg;
                float sd = rstd[r], m_ = mu[r];
                #pragma unroll
                for (int nt = 0; nt < 8; nt++)
                    kpre[(size_t)r * Dd + nt * 16 + l15] = acc[mt][nt][reg] * sd + bd[nt] - sd * m_ * gd[nt];
            }
    } else {
        #pragma unroll
        for (int mt = 0; mt < 2; mt++)
            #pragma unroll
            for (int reg = 0; reg < 4; reg++) {
                int r = brow + w * 32 + mt * 16 + quad * 4 + reg;
                #pragma unroll
                for (int nt = 0; nt < 2; nt++)     // n = nt*16+l15 in 0..31
                    wout[(size_t)r * Hn + nt * 16 + l15] = acc[mt][nt][reg];
            }
    }
}

// ---------------- 6) copy cache defaults into outputs (fp32) -------------
__global__ void copy_cache(const float* __restrict__ kc, const float* __restrict__ kcs,
                           float* __restrict__ dk, float* __restrict__ dks)
{
    int g = blockIdx.x * 256 + threadIdx.x;          // 262144 threads, 8 floats each
    ((float4*)dk)[2 * g]     = ((const float4*)kc)[2 * g];
    ((float4*)dk)[2 * g + 1] = ((const float4*)kc)[2 * g + 1];
    if (g < Lc / 8) {
        ((float4*)dks)[2 * g]     = ((const float4*)kcs)[2 * g];
        ((float4*)dks)[2 * g + 1] = ((const float4*)kcs)[2 * g + 1];
    }
}

// ---------------- 7) K-branch: RoPE + Hadamard (MFMA) + quant + scatter ----
template <int IS_K>
__global__ __launch_bounds__(256) void post_kernel(
    const float* src,               // k: [M][128] (fp32)
    const u16* __restrict__ ht,     // transposed hadamard [n][k] bf16
    const float* __restrict__ cosr, const float* __restrict__ sinr,  // [S][128] fp32
    const int* __restrict__ idx,    // k only
    float* dstq, float* __restrict__ dsts)
{
    constexpr int RP = 136;  // padded LDS row stride (elements)
    __shared__ __align__(16) u16 sA[32 * RP];
    __shared__ __align__(16) u16 sB[128 * RP];
    __shared__ float pamax[32][2];
    __shared__ int sidx[32];

    int blk = blockIdx.x, tid = threadIdx.x;

    { // stage hadamard^T into padded LDS
        int n = tid >> 1, kk0 = (tid & 1) * 64;
        const u16x8* gp = (const u16x8*)(ht + n * Dd + kk0);
        u16* lb = sB + n * RP + kk0;
        #pragma unroll
        for (int j = 0; j < 8; j++) *(u16x8*)(lb + j * 8) = gp[j];
    }
    { // stage 32 rows with RoPE applied (fp32 reads -> bf16 LDS)
        int r = tid >> 3, c = tid & 7;
        int d0 = c * 16;
        int s_ = IS_K ? ((blk * 32 + r) & (Sdim - 1)) : (blk & (Sdim - 1));
        const float* srow = src + (size_t)blk * 4096 + r * Dd;   // same addr law for q and k
        int p0 = (d0 + 64) & 127;
        float sign = (d0 < 64) ? -1.f : 1.f;
        float vv[16], pv[16], cv[16], sv[16];
        #pragma unroll
        for (int j = 0; j < 4; j++) {
            float4 a = *(const float4*)(srow + d0 + 4 * j);
            float4 p = *(const float4*)(srow + p0 + 4 * j);
            float4 cc = *(const float4*)(cosr + (size_t)s_ * Dd + d0 + 4 * j);
            float4 sc = *(const float4*)(sinr + (size_t)s_ * Dd + d0 + 4 * j);
            vv[4*j] = a.x; vv[4*j+1] = a.y; vv[4*j+2] = a.z; vv[4*j+3] = a.w;
            pv[4*j] = p.x; pv[4*j+1] = p.y; pv[4*j+2] = p.z; pv[4*j+3] = p.w;
            cv[4*j] = cc.x; cv[4*j+1] = cc.y; cv[4*j+2] = cc.z; cv[4*j+3] = cc.w;
            sv[4*j] = sc.x; sv[4*j+1] = sc.y; sv[4*j+2] = sc.z; sv[4*j+3] = sc.w;
        }
        __align__(16) u16 o[16];
        #pragma unroll
        for (int i = 0; i < 16; i++)
            o[i] = f2bf(vv[i] * cv[i] + sign * pv[i] * sv[i]);
        u16* la = sA + r * RP + d0;
        *(u16x8*)la = *(const u16x8*)o;
        *(u16x8*)(la + 8) = *((const u16x8*)o + 1);
        if (IS_K && tid < 32) sidx[tid] = idx[blk * 32 + tid];
    }
    __syncthreads();

    int w = tid >> 6, lane = tid & 63, quad = lane >> 4, l15 = lane & 15;
    int rs = (w & 1) * 16, cg = (w >> 1) * 64;
    f32x4 acc[4] = {};
    #pragma unroll
    for (int kb = 0; kb < 4; kb++) {
        bf16x8 a = *(const bf16x8*)(sA + (rs + l15) * RP + kb * 32 + quad * 8);
        #pragma unroll
        for (int nt = 0; nt < 4; nt++) {
            bf16x8 b = *(const bf16x8*)(sB + (cg + nt * 16 + l15) * RP + kb * 32 + quad * 8);
            acc[nt] = __builtin_amdgcn_mfma_f32_16x16x32_bf16(a, b, acc[nt], 0, 0, 0);
        }
    }
    // per-row partial absmax over this wave's 64 cols
    #pragma unroll
    for (int reg = 0; reg < 4; reg++) {
        float m = 0.f;
        #pragma unroll
        for (int nt = 0; nt < 4; nt++) m = fmaxf(m, fabsf(acc[nt][reg]));
        m = fmaxf(m, __shfl_xor(m, 8));
        m = fmaxf(m, __shfl_xor(m, 4));
        m = fmaxf(m, __shfl_xor(m, 2));
        m = fmaxf(m, __shfl_xor(m, 1));
        if (l15 == 0) pamax[rs + quad * 4 + reg][w >> 1] = m;
    }
    __syncthreads();
    #pragma unroll
    for (int reg = 0; reg < 4; reg++) {
        int r = rs + quad * 4 + reg;
        float am = fmaxf(pamax[r][0], pamax[r][1]);
        float scale = fmaxf(am * (1.f / 127.f), 1e-8f);
        float inv = 1.f / scale;
        size_t dro = IS_K ? (size_t)sidx[r] * Dd : (size_t)blk * 4096 + (size_t)r * Dd;
        #pragma unroll
        for (int nt = 0; nt < 4; nt++)
            dstq[dro + cg + nt * 16 + l15] = rintf(acc[nt][reg] * inv);
        if (l15 == 0 && (w >> 1) == 0)
            dsts[IS_K ? sidx[r] : blk * Hn + r] = scale;
    }
}

// ---------------- launch ------------------------------------------------
extern "C" void kernel_launch(void* const* d_in, const int* in_sizes, int n_in,
                              void* d_out, int out_size, void* d_ws, size_t ws_size,
                              hipStream_t stream) {
    (void)in_sizes; (void)n_in; (void)out_size; (void)ws_size;
    const float* x    = (const float*)d_in[0];
    const float* qn   = (const float*)d_in[1];
    const float* qns  = (const float*)d_in[2];
    const float* wqb  = (const float*)d_in[3];
    const float* wqbs = (const float*)d_in[4];
    const float* wk   = (const float*)d_in[5];
    const float* wpj  = (const float*)d_in[6];
    const float* g    = (const float*)d_in[7];
    const float* b    = (const float*)d_in[8];
    const float* cosr = (const float*)d_in[9];
    const float* sinr = (const float*)d_in[10];
    const float* hq   = (const float*)d_in[11];
    const float* hk   = (const float*)d_in[12];
    const float* kc   = (const float*)d_in[13];
    const float* kcs  = (const float*)d_in[14];
    const int*   idx  = (const int*)d_in[15];

    // ws layout
    char* ws = (char*)d_ws;
    size_t o = 0;
    u16* xb  = (u16*)(ws + o); o += (size_t)Mrows * Hdim * 2;   // 33.55 MB
    u16* wt  = (u16*)(ws + o); o += (size_t)NFULL * Hdim * 2;   // 17.83 MB
    u16* hqt = (u16*)(ws + o); o += Dd * Dd * 2;
    u16* hkt = (u16*)(ws + o); o += Dd * Dd * 2;
    float* rmsb  = (float*)(ws + o); o += (size_t)Mrows * 4;
    float* mub   = (float*)(ws + o); o += (size_t)Mrows * 4;
    float* rstdb = (float*)(ws + o); o += (size_t)Mrows * 4;
    float* bdotb = (float*)(ws + o); o += 512;
    float* gdotb = (float*)(ws + o); o += 512;
    float* kpre  = (float*)(ws + o); o += (size_t)Mrows * Dd * 4;  // 4.19 MB

    float* out = (float*)d_out;
    float* oq  = out;                             // [M][4096]
    float* oqs = oq  + (size_t)Mrows * HnD;       // [M][32]
    float* ok  = oqs + (size_t)Mrows * Hn;        // [L][128]
    float* oks = ok  + (size_t)Lc * Dd;           // [L]
    float* ow  = oks + Lc;                        // [M][32]

    stats_cvt<<<Mrows, 256, 0, stream>>>(x, xb, rmsb, mub, rstdb);
    prep_wt<<<dim3(Hdim / 64, NFULL / 64), 256, 0, stream>>>(wqb, qn, qns, wk, g, wpj, wt);
    transpose_h<<<2, 256, 0, stream>>>(hq, hk, hqt, hkt);
    bg_dot<<<Dd, 256, 0, stream>>>(wk, g, b, bdotb, gdotb);
    main_gemm<<<dim3(Mrows / 128, NFULL / 128), 256, 0, stream>>>(
        xb, wt, rmsb, mub, rstdb, wqbs, bdotb, gdotb, hqt, cosr, sinr, oq, oqs, kpre, ow);
    copy_cache<<<(Lc * Dd / 8) / 256, 256, 0, stream>>>(kc, kcs, ok, oks);
    post_kernel<1><<<Mrows / 32, 256, 0, stream>>>(kpre, hkt, cosr, sinr, idx, ok, oks);
}

// Round 3
// 525.173 us; speedup vs baseline: 1.0999x; 1.0562x over previous
//
#include <hip/hip_runtime.h>
#include <hip/hip_bf16.h>
#include <stdint.h>

// ---------------- problem constants (from setup_inputs) ----------------
constexpr int Mrows = 8192;   // B*S
constexpr int Hdim  = 2048;   // K of main GEMM
constexpr int Sdim  = 4096;
constexpr int HnD   = 4096;   // Hn*D
constexpr int Hn    = 32;
constexpr int Dd    = 128;
constexpr int Lc    = 16384;
constexpr int NFULL = 4352;   // 4096 q + 128 k + 32 w + 96 zero pad (17 tiles of 256)

typedef unsigned short u16;
typedef __attribute__((ext_vector_type(8))) short    bf16x8;
typedef __attribute__((ext_vector_type(4))) float    f32x4;
typedef __attribute__((ext_vector_type(8))) unsigned short u16x8;

__device__ __forceinline__ float bf2f(u16 u) {
    union { unsigned int i; float f; } v; v.i = ((unsigned int)u) << 16; return v.f;
}
__device__ __forceinline__ u16 f2bf(float f) {
    union { float f; unsigned int i; } v; v.f = f;
    unsigned int x = v.i;
    return (u16)((x + 0x7fffu + ((x >> 16) & 1u)) >> 16);   // RNE
}
__device__ __forceinline__ void gload_lds16(const void* g, void* l) {
    __builtin_amdgcn_global_load_lds(
        (const __attribute__((address_space(1))) void*)g,
        (__attribute__((address_space(3))) void*)l, 16, 0, 0);
}

// ------- 1) per-row stats (rms, mu, rstd) + fp32 -> bf16 copy of x -------
__global__ __launch_bounds__(256) void stats_cvt(
    const float* __restrict__ x, u16* __restrict__ xb, float* __restrict__ rms,
    float* __restrict__ mu, float* __restrict__ rstd)
{
    int r = blockIdx.x, t = threadIdx.x;
    const float4* xr = (const float4*)(x + (size_t)r * Hdim);
    float4 a = xr[2 * t], bq = xr[2 * t + 1];
    float v[8] = {a.x, a.y, a.z, a.w, bq.x, bq.y, bq.z, bq.w};
    float s = 0.f, ss = 0.f;
    __align__(16) u16 o[8];
    #pragma unroll
    for (int i = 0; i < 8; i++) { s += v[i]; ss += v[i] * v[i]; o[i] = f2bf(v[i]); }
    ((u16x8*)(xb + (size_t)r * Hdim))[t] = *(const u16x8*)o;
    for (int oo = 32; oo > 0; oo >>= 1) { s += __shfl_down(s, oo); ss += __shfl_down(ss, oo); }
    __shared__ float as[4], ass[4];
    if ((t & 63) == 0) { as[t >> 6] = s; ass[t >> 6] = ss; }
    __syncthreads();
    if (t == 0) {
        float S1 = as[0] + as[1] + as[2] + as[3];
        float S2 = ass[0] + ass[1] + ass[2] + ass[3];
        float mean = S1 / Hdim, msq = S2 / Hdim;
        rms[r]  = rsqrtf(msq + 1e-6f);
        mu[r]   = mean;
        rstd[r] = rsqrtf(msq - mean * mean + 1e-6f);
    }
}

// ---------------- 2) build B'^T = [c1*wqb | g*wk | wproj | 0]^T, [NFULL][H] ---
__global__ __launch_bounds__(256) void prep_wt(
    const float* __restrict__ wqb, const float* __restrict__ qn, const float* __restrict__ qns,
    const float* __restrict__ wk,  const float* __restrict__ g,  const float* __restrict__ wproj,
    u16* __restrict__ wt)
{
    __shared__ u16 tile[64][72];
    int k0 = blockIdx.x * 64, n0 = blockIdx.y * 64;
    int t = threadIdx.x;
    int lk = t >> 2, lc0 = (t & 3) * 16;
    int k = k0 + lk;
    float c1k = qn[k] * qns[k];
    float gk  = g[k];
    #pragma unroll
    for (int i = 0; i < 16; i++) {
        int n = n0 + lc0 + i;
        float val;
        if (n < 4096)      val = wqb[(size_t)k * HnD + n] * c1k;
        else if (n < 4224) val = wk[k * Dd + (n - 4096)] * gk;
        else if (n < 4256) val = wproj[k * Hn + (n - 4224)];
        else               val = 0.f;
        tile[lk][lc0 + i] = f2bf(val);
    }
    __syncthreads();
    int ln = t >> 2, lk0 = (t & 3) * 16;
    __align__(16) u16 o[16];
    #pragma unroll
    for (int i = 0; i < 16; i++) o[i] = tile[lk0 + i][ln];
    u16* dst = wt + (size_t)(n0 + ln) * Hdim + k0 + lk0;
    *(u16x8*)dst = *(const u16x8*)o;
    *(u16x8*)(dst + 8) = *((const u16x8*)o + 1);
}

// ------- 3) transpose hadamard matrices to bf16 (LDS-tiled, coalesced) ----
__global__ __launch_bounds__(256) void transpose_h(
    const float* __restrict__ hq, const float* __restrict__ hk,
    u16* __restrict__ hqt, u16* __restrict__ hkt)
{
    __shared__ float tile[128][129];
    const float* src = blockIdx.x ? hk : hq;
    u16* dst = blockIdx.x ? hkt : hqt;
    int t = threadIdx.x;
    int r = t >> 1, h = (t & 1) * 64;
    #pragma unroll
    for (int j = 0; j < 16; j++) {
        float4 v = *(const float4*)(src + r * Dd + h + 4 * j);
        tile[r][h + 4 * j]     = v.x;
        tile[r][h + 4 * j + 1] = v.y;
        tile[r][h + 4 * j + 2] = v.z;
        tile[r][h + 4 * j + 3] = v.w;
    }
    __syncthreads();
    #pragma unroll
    for (int j0 = 0; j0 < 64; j0 += 8) {
        __align__(16) u16 o[8];
        #pragma unroll
        for (int j = 0; j < 8; j++) o[j] = f2bf(tile[h + j0 + j][r]);
        *(u16x8*)(dst + r * Dd + h + j0) = *(const u16x8*)o;
    }
}

// ---------------- 4) bdot[n]=sum_k b*wk, gdot[n]=sum_k g*wk ------------
__global__ __launch_bounds__(256) void bg_dot(
    const float* __restrict__ wk, const float* __restrict__ g, const float* __restrict__ b,
    float* __restrict__ bdot, float* __restrict__ gdot)
{
    int n = blockIdx.x, t = threadIdx.x;
    float sb = 0.f, sg = 0.f;
    for (int k = t; k < Hdim; k += 256) {
        float w = wk[k * Dd + n];
        sb += b[k] * w;
        sg += g[k] * w;
    }
    for (int o = 32; o > 0; o >>= 1) { sb += __shfl_down(sb, o); sg += __shfl_down(sg, o); }
    __shared__ float rb[4], rg[4];
    if ((t & 63) == 0) { rb[t >> 6] = sb; rg[t >> 6] = sg; }
    __syncthreads();
    if (t == 0) { bdot[n] = rb[0] + rb[1] + rb[2] + rb[3]; gdot[n] = rg[0] + rg[1] + rg[2] + rg[3]; }
}

// ---------------- 5) main fused GEMM, 256x256 8-phase template -------------
// BM=BN=256, BK=64, 512 thr (8 waves, 4M x 2N: each wave owns 64 rows x one
// full 128-col head -> in-register RoPE partner nt^4). Double-buffered 128 KiB
// LDS, raw s_barrier (no vmcnt drain), counted prefetch (t+1 issued in ph0/ph1
// of tile t), XOR swizzle chunk^=row&7 on BOTH sides (pre-swizzled gload src +
// swizzled ds_read; rule #21), sched_barrier after asm waitcnt (rule #18),
// setprio around MFMA clusters (T5). Fused q epilogue in per-wave P regions.
#define LDA_(buf, mt, kk) (*(const bf16x8*)(lds + (buf)*65536 + \
    (wr*64 + (mt)*16 + l15) * 128 + ((((kk)*4 + quad) ^ (l15 & 7)) * 16)))
#define LDB_(buf, nt, kk) (*(const bf16x8*)(lds + (buf)*65536 + 32768 + \
    (wc*128 + (nt)*16 + l15) * 128 + ((((kk)*4 + quad) ^ (l15 & 7)) * 16)))
#define STAGE_A(buf, g, kt) gload_lds16( \
    Ab + (size_t)((g)*64 + r64) * Hdim + (kt)*64 + cswz, \
    ldst + (buf)*65536 + (g)*8192)
#define STAGE_B(buf, g, kt) gload_lds16( \
    Bb + (size_t)((g)*64 + r64) * Hdim + (kt)*64 + cswz, \
    ldst + (buf)*65536 + 32768 + (g)*8192)

__global__ __launch_bounds__(512, 2) void main_gemm(
    const u16* __restrict__ A, const u16* __restrict__ Bt,
    const float* __restrict__ rms, const float* __restrict__ mu, const float* __restrict__ rstd,
    const float* __restrict__ qbs,
    const float* __restrict__ bdot, const float* __restrict__ gdot,
    const u16* __restrict__ hqt,
    const float* __restrict__ cosr, const float* __restrict__ sinr,
    float* __restrict__ oq, float* __restrict__ oqs,
    float* __restrict__ kpre, float* __restrict__ wout)
{
    __shared__ __align__(16) char lds[131072];

    int tid = threadIdx.x;
    int w = tid >> 6, lane = tid & 63, quad = lane >> 4, l15 = lane & 15;
    int wr = w >> 1, wc = w & 1;                 // 4 M-waves x 2 N-waves
    // bijective XCD swizzle: 544 blocks = 8 XCDs x 68
    int lin = blockIdx.x + 32 * blockIdx.y;
    int wg = (lin & 7) * 68 + (lin >> 3);
    int bm = wg & 31, bn = wg >> 5;
    int brow = bm * 256;

    const u16* Ab = A  + (size_t)brow * Hdim;
    const u16* Bb = Bt + (size_t)(bn * 256) * Hdim;

    // staging geometry: thread t stages row g*64 + (t>>3), chunk (t&7) of the
    // [256][64]-bf16 tile; source chunk pre-swizzled by row&7.
    int r64 = tid >> 3;
    int cswz = (((tid & 7) ^ (r64 & 7)) * 8);    // element offset
    char* ldst = lds + (tid >> 6) * 1024;        // wave-uniform dest part

    f32x4 acc[4][8] = {};

    // prologue: stage tile 0 into buf 0
    #pragma unroll
    for (int g = 0; g < 4; g++) { STAGE_A(0, g, 0); STAGE_B(0, g, 0); }

    for (int t = 0; t < 32; t++) {
        int buf = t & 1, nb = buf ^ 1;
        bool pf = (t + 1 < 32);
        asm volatile("s_waitcnt vmcnt(0)" ::: "memory");
        __builtin_amdgcn_sched_barrier(0);
        __builtin_amdgcn_s_barrier();

        bf16x8 a0[4], a1[4], bfr[4];
        // ---- ph0: A(kk0) + B(kk0, n0-3); prefetch A(t+1) ----
        #pragma unroll
        for (int mt = 0; mt < 4; mt++) a0[mt] = LDA_(buf, mt, 0);
        #pragma unroll
        for (int nt = 0; nt < 4; nt++) bfr[nt] = LDB_(buf, nt, 0);
        if (pf) { STAGE_A(nb, 0, t+1); STAGE_A(nb, 1, t+1); STAGE_A(nb, 2, t+1); STAGE_A(nb, 3, t+1); }
        asm volatile("s_waitcnt lgkmcnt(0)" ::: "memory");
        __builtin_amdgcn_sched_barrier(0);
        __builtin_amdgcn_s_setprio(1);
        #pragma unroll
        for (int mt = 0; mt < 4; mt++)
            #pragma unroll
            for (int nt = 0; nt < 4; nt++)
                acc[mt][nt] = __builtin_amdgcn_mfma_f32_16x16x32_bf16(a0[mt], bfr[nt], acc[mt][nt], 0, 0, 0);
        __builtin_amdgcn_s_setprio(0);
        __builtin_amdgcn_s_barrier();
        // ---- ph1: B(kk0, n4-7); prefetch B(t+1) ----
        #pragma unroll
        for (int nt = 0; nt < 4; nt++) bfr[nt] = LDB_(buf, 4 + nt, 0);
        if (pf) { STAGE_B(nb, 0, t+1); STAGE_B(nb, 1, t+1); STAGE_B(nb, 2, t+1); STAGE_B(nb, 3, t+1); }
        asm volatile("s_waitcnt lgkmcnt(0)" ::: "memory");
        __builtin_amdgcn_sched_barrier(0);
        __builtin_amdgcn_s_setprio(1);
        #pragma unroll
        for (int mt = 0; mt < 4; mt++)
            #pragma unroll
            for (int nt = 0; nt < 4; nt++)
                acc[mt][4 + nt] = __builtin_amdgcn_mfma_f32_16x16x32_bf16(a0[mt], bfr[nt], acc[mt][4 + nt], 0, 0, 0);
        __builtin_amdgcn_s_setprio(0);
        __builtin_amdgcn_s_barrier();
        // ---- ph2: A(kk1) + B(kk1, n0-3) ----
        #pragma unroll
        for (int mt = 0; mt < 4; mt++) a1[mt] = LDA_(buf, mt, 1);
        #pragma unroll
        for (int nt = 0; nt < 4; nt++) bfr[nt] = LDB_(buf, nt, 1);
        asm volatile("s_waitcnt lgkmcnt(0)" ::: "memory");
        __builtin_amdgcn_sched_barrier(0);
        __builtin_amdgcn_s_setprio(1);
        #pragma unroll
        for (int mt = 0; mt < 4; mt++)
            #pragma unroll
            for (int nt = 0; nt < 4; nt++)
                acc[mt][nt] = __builtin_amdgcn_mfma_f32_16x16x32_bf16(a1[mt], bfr[nt], acc[mt][nt], 0, 0, 0);
        __builtin_amdgcn_s_setprio(0);
        __builtin_amdgcn_s_barrier();
        // ---- ph3: B(kk1, n4-7) ----
        #pragma unroll
        for (int nt = 0; nt < 4; nt++) bfr[nt] = LDB_(buf, 4 + nt, 1);
        asm volatile("s_waitcnt lgkmcnt(0)" ::: "memory");
        __builtin_amdgcn_sched_barrier(0);
        __builtin_amdgcn_s_setprio(1);
        #pragma unroll
        for (int mt = 0; mt < 4; mt++)
            #pragma unroll
            for (int nt = 0; nt < 4; nt++)
                acc[mt][4 + nt] = __builtin_amdgcn_mfma_f32_16x16x32_bf16(a1[mt], bfr[nt], acc[mt][4 + nt], 0, 0, 0);
        __builtin_amdgcn_s_setprio(0);
        __builtin_amdgcn_s_barrier();
    }

    if (bn < 16) {
        // -------- fused q epilogue: scale -> RoPE -> P (per-wave LDS, swizzled)
        //          -> hadamard MFMA -> absmax -> quant -> store
        __syncthreads();
        int head = bn * 2 + wc;                  // 0..31
        char* Pw = lds + w * 16384;              // per-wave [64][256B] region
        float qb[8];
        #pragma unroll
        for (int nt = 0; nt < 8; nt++) qb[nt] = qbs[head * 128 + nt * 16 + l15];
        #pragma unroll
        for (int mt = 0; mt < 4; mt++) {
            float y[8][4];
            #pragma unroll
            for (int reg = 0; reg < 4; reg++) {
                float rv = rms[brow + wr * 64 + mt * 16 + quad * 4 + reg];
                #pragma unroll
                for (int nt = 0; nt < 8; nt++) y[nt][reg] = acc[mt][nt][reg] * rv * qb[nt];
            }
            #pragma unroll
            for (int reg = 0; reg < 4; reg++) {
                int rp = mt * 16 + quad * 4 + reg;          // 0..63 local row
                int s_ = (brow + wr * 64 + rp) & (Sdim - 1);
                const float* cr = cosr + (size_t)s_ * Dd + l15;
                const float* sr = sinr + (size_t)s_ * Dd + l15;
                int sw = (rp & 7) << 4;
                #pragma unroll
                for (int nt = 0; nt < 8; nt++) {
                    float c  = cr[nt * 16];
                    float sv = sr[nt * 16];
                    float sign = (nt < 4) ? -1.f : 1.f;
                    float o = y[nt][reg] * c + sign * y[nt ^ 4][reg] * sv;   // fp32 RoPE
                    int colb = (nt * 16 + l15) * 2;
                    *(u16*)(Pw + rp * 256 + (colb ^ sw)) = f2bf(o);
                }
            }
        }
        __syncthreads();
        #pragma unroll
        for (int mt = 0; mt < 4; mt++) {
            bf16x8 pa[4];
            #pragma unroll
            for (int kb = 0; kb < 4; kb++) {
                int row = mt * 16 + l15;
                pa[kb] = *(const bf16x8*)(Pw + row * 256 + ((kb * 64 + quad * 16) ^ ((row & 7) << 4)));
            }
            f32x4 a2[8] = {};
            #pragma unroll
            for (int nt = 0; nt < 8; nt++) {
                #pragma unroll
                for (int kb = 0; kb < 4; kb++) {
                    bf16x8 hb = *(const bf16x8*)(hqt + (size_t)(nt * 16 + l15) * Dd + kb * 32 + quad * 8);
                    a2[nt] = __builtin_amdgcn_mfma_f32_16x16x32_bf16(pa[kb], hb, a2[nt], 0, 0, 0);
                }
            }
            #pragma unroll
            for (int reg = 0; reg < 4; reg++) {
                float m = 0.f;
                #pragma unroll
                for (int nt = 0; nt < 8; nt++) m = fmaxf(m, fabsf(a2[nt][reg]));
                m = fmaxf(m, __shfl_xor(m, 8));
                m = fmaxf(m, __shfl_xor(m, 4));
                m = fmaxf(m, __shfl_xor(m, 2));
                m = fmaxf(m, __shfl_xor(m, 1));
                float scale = fmaxf(m * (1.f / 127.f), 1e-8f);
                float inv = 1.f / scale;
                int r = brow + wr * 64 + mt * 16 + quad * 4 + reg;
                float* orow = oq + (size_t)r * HnD + head * 128;
                #pragma unroll
                for (int nt = 0; nt < 8; nt++)
                    orow[nt * 16 + l15] = rintf(a2[nt][reg] * inv);
                if (l15 == 0) oqs[(size_t)r * Hn + head] = scale;
            }
        }
    } else {                       // bn == 16: wc==0 -> k cols, wc==1 -> w cols
        if (wc == 0) {
            float bd[8], gd[8];
            #pragma unroll
            for (int nt = 0; nt < 8; nt++) { bd[nt] = bdot[nt * 16 + l15]; gd[nt] = gdot[nt * 16 + l15]; }
            #pragma unroll
            for (int mt = 0; mt < 4; mt++)
                #pragma unroll
                for (int reg = 0; reg < 4; reg++) {
                    int r = brow + wr * 64 + mt * 16 + quad * 4 + reg;
                    float sd = rstd[r], m_ = mu[r];
                    #pragma unroll
                    for (int nt = 0; nt < 8; nt++)
                        kpre[(size_t)r * Dd + nt * 16 + l15] = acc[mt][nt][reg] * sd + bd[nt] - sd * m_ * gd[nt];
                }
        } else {
            #pragma unroll
            for (int mt = 0; mt < 4; mt++)
                #pragma unroll
                for (int reg = 0; reg < 4; reg++) {
                    int r = brow + wr * 64 + mt * 16 + quad * 4 + reg;
                    #pragma unroll
                    for (int nt = 0; nt < 2; nt++)       // n = nt*16+l15 in 0..31
                        wout[(size_t)r * Hn + nt * 16 + l15] = acc[mt][nt][reg];
                }
        }
    }
}

// ---------------- 6) copy cache defaults into outputs (fp32) -------------
__global__ void copy_cache(const float* __restrict__ kc, const float* __restrict__ kcs,
                           float* __restrict__ dk, float* __restrict__ dks)
{
    int g = blockIdx.x * 256 + threadIdx.x;          // 262144 threads, 8 floats each
    ((float4*)dk)[2 * g]     = ((const float4*)kc)[2 * g];
    ((float4*)dk)[2 * g + 1] = ((const float4*)kc)[2 * g + 1];
    if (g < Lc / 8) {
        ((float4*)dks)[2 * g]     = ((const float4*)kcs)[2 * g];
        ((float4*)dks)[2 * g + 1] = ((const float4*)kcs)[2 * g + 1];
    }
}

// ---------------- 7) K-branch: RoPE + Hadamard (MFMA) + quant + scatter ----
template <int IS_K>
__global__ __launch_bounds__(256) void post_kernel(
    const float* src,               // k: [M][128] (fp32)
    const u16* __restrict__ ht,     // transposed hadamard [n][k] bf16
    const float* __restrict__ cosr, const float* __restrict__ sinr,  // [S][128] fp32
    const int* __restrict__ idx,    // k only
    float* dstq, float* __restrict__ dsts)
{
    constexpr int RP = 136;  // padded LDS row stride (elements)
    __shared__ __align__(16) u16 sA[32 * RP];
    __shared__ __align__(16) u16 sB[128 * RP];
    __shared__ float pamax[32][2];
    __shared__ int sidx[32];

    int blk = blockIdx.x, tid = threadIdx.x;

    { // stage hadamard^T into padded LDS
        int n = tid >> 1, kk0 = (tid & 1) * 64;
        const u16x8* gp = (const u16x8*)(ht + n * Dd + kk0);
        u16* lb = sB + n * RP + kk0;
        #pragma unroll
        for (int j = 0; j < 8; j++) *(u16x8*)(lb + j * 8) = gp[j];
    }
    { // stage 32 rows with RoPE applied (fp32 reads -> bf16 LDS)
        int r = tid >> 3, c = tid & 7;
        int d0 = c * 16;
        int s_ = IS_K ? ((blk * 32 + r) & (Sdim - 1)) : (blk & (Sdim - 1));
        const float* srow = src + (size_t)blk * 4096 + r * Dd;
        int p0 = (d0 + 64) & 127;
        float sign = (d0 < 64) ? -1.f : 1.f;
        float vv[16], pv[16], cv[16], sv[16];
        #pragma unroll
        for (int j = 0; j < 4; j++) {
            float4 a = *(const float4*)(srow + d0 + 4 * j);
            float4 p = *(const float4*)(srow + p0 + 4 * j);
            float4 cc = *(const float4*)(cosr + (size_t)s_ * Dd + d0 + 4 * j);
            float4 sc = *(const float4*)(sinr + (size_t)s_ * Dd + d0 + 4 * j);
            vv[4*j] = a.x; vv[4*j+1] = a.y; vv[4*j+2] = a.z; vv[4*j+3] = a.w;
            pv[4*j] = p.x; pv[4*j+1] = p.y; pv[4*j+2] = p.z; pv[4*j+3] = p.w;
            cv[4*j] = cc.x; cv[4*j+1] = cc.y; cv[4*j+2] = cc.z; cv[4*j+3] = cc.w;
            sv[4*j] = sc.x; sv[4*j+1] = sc.y; sv[4*j+2] = sc.z; sv[4*j+3] = sc.w;
        }
        __align__(16) u16 o[16];
        #pragma unroll
        for (int i = 0; i < 16; i++)
            o[i] = f2bf(vv[i] * cv[i] + sign * pv[i] * sv[i]);
        u16* la = sA + r * RP + d0;
        *(u16x8*)la = *(const u16x8*)o;
        *(u16x8*)(la + 8) = *((const u16x8*)o + 1);
        if (IS_K && tid < 32) sidx[tid] = idx[blk * 32 + tid];
    }
    __syncthreads();

    int w = tid >> 6, lane = tid & 63, quad = lane >> 4, l15 = lane & 15;
    int rs = (w & 1) * 16, cg = (w >> 1) * 64;
    f32x4 acc[4] = {};
    #pragma unroll
    for (int kb = 0; kb < 4; kb++) {
        bf16x8 a = *(const bf16x8*)(sA + (rs + l15) * RP + kb * 32 + quad * 8);
        #pragma unroll
        for (int nt = 0; nt < 4; nt++) {
            bf16x8 b = *(const bf16x8*)(sB + (cg + nt * 16 + l15) * RP + kb * 32 + quad * 8);
            acc[nt] = __builtin_amdgcn_mfma_f32_16x16x32_bf16(a, b, acc[nt], 0, 0, 0);
        }
    }
    #pragma unroll
    for (int reg = 0; reg < 4; reg++) {
        float m = 0.f;
        #pragma unroll
        for (int nt = 0; nt < 4; nt++) m = fmaxf(m, fabsf(acc[nt][reg]));
        m = fmaxf(m, __shfl_xor(m, 8));
        m = fmaxf(m, __shfl_xor(m, 4));
        m = fmaxf(m, __shfl_xor(m, 2));
        m = fmaxf(m, __shfl_xor(m, 1));
        if (l15 == 0) pamax[rs + quad * 4 + reg][w >> 1] = m;
    }
    __syncthreads();
    #pragma unroll
    for (int reg = 0; reg < 4; reg++) {
        int r = rs + quad * 4 + reg;
        float am = fmaxf(pamax[r][0], pamax[r][1]);
        float scale = fmaxf(am * (1.f / 127.f), 1e-8f);
        float inv = 1.f / scale;
        size_t dro = IS_K ? (size_t)sidx[r] * Dd : (size_t)blk * 4096 + (size_t)r * Dd;
        #pragma unroll
        for (int nt = 0; nt < 4; nt++)
            dstq[dro + cg + nt * 16 + l15] = rintf(acc[nt][reg] * inv);
        if (l15 == 0 && (w >> 1) == 0)
            dsts[IS_K ? sidx[r] : blk * Hn + r] = scale;
    }
}

// ---------------- launch ------------------------------------------------
extern "C" void kernel_launch(void* const* d_in, const int* in_sizes, int n_in,
                              void* d_out, int out_size, void* d_ws, size_t ws_size,
                              hipStream_t stream) {
    (void)in_sizes; (void)n_in; (void)out_size; (void)ws_size;
    const float* x    = (const float*)d_in[0];
    const float* qn   = (const float*)d_in[1];
    const float* qns  = (const float*)d_in[2];
    const float* wqb  = (const float*)d_in[3];
    const float* wqbs = (const float*)d_in[4];
    const float* wk   = (const float*)d_in[5];
    const float* wpj  = (const float*)d_in[6];
    const float* g    = (const float*)d_in[7];
    const float* b    = (const float*)d_in[8];
    const float* cosr = (const float*)d_in[9];
    const float* sinr = (const float*)d_in[10];
    const float* hq   = (const float*)d_in[11];
    const float* hk   = (const float*)d_in[12];
    const float* kc   = (const float*)d_in[13];
    const float* kcs  = (const float*)d_in[14];
    const int*   idx  = (const int*)d_in[15];

    // ws layout
    char* ws = (char*)d_ws;
    size_t o = 0;
    u16* xb  = (u16*)(ws + o); o += (size_t)Mrows * Hdim * 2;   // 33.55 MB
    u16* wt  = (u16*)(ws + o); o += (size_t)NFULL * Hdim * 2;   // 17.83 MB
    u16* hqt = (u16*)(ws + o); o += Dd * Dd * 2;
    u16* hkt = (u16*)(ws + o); o += Dd * Dd * 2;
    float* rmsb  = (float*)(ws + o); o += (size_t)Mrows * 4;
    float* mub   = (float*)(ws + o); o += (size_t)Mrows * 4;
    float* rstdb = (float*)(ws + o); o += (size_t)Mrows * 4;
    float* bdotb = (float*)(ws + o); o += 512;
    float* gdotb = (float*)(ws + o); o += 512;
    float* kpre  = (float*)(ws + o); o += (size_t)Mrows * Dd * 4;  // 4.19 MB

    float* out = (float*)d_out;
    float* oq  = out;                             // [M][4096]
    float* oqs = oq  + (size_t)Mrows * HnD;       // [M][32]
    float* ok  = oqs + (size_t)Mrows * Hn;        // [L][128]
    float* oks = ok  + (size_t)Lc * Dd;           // [L]
    float* ow  = oks + Lc;                        // [M][32]

    stats_cvt<<<Mrows, 256, 0, stream>>>(x, xb, rmsb, mub, rstdb);
    prep_wt<<<dim3(Hdim / 64, NFULL / 64), 256, 0, stream>>>(wqb, qn, qns, wk, g, wpj, wt);
    transpose_h<<<2, 256, 0, stream>>>(hq, hk, hqt, hkt);
    bg_dot<<<Dd, 256, 0, stream>>>(wk, g, b, bdotb, gdotb);
    main_gemm<<<dim3(32, 17), 512, 0, stream>>>(
        xb, wt, rmsb, mub, rstdb, wqbs, bdotb, gdotb, hqt, cosr, sinr, oq, oqs, kpre, ow);
    copy_cache<<<(Lc * Dd / 8) / 256, 256, 0, stream>>>(kc, kcs, ok, oks);
    post_kernel<1><<<Mrows / 32, 256, 0, stream>>>(kpre, hkt, cosr, sinr, idx, ok, oks);
}

// Round 4
// 508.299 us; speedup vs baseline: 1.1364x; 1.0332x over previous
//
#include <hip/hip_runtime.h>
#include <hip/hip_bf16.h>
#include <stdint.h>

// ---------------- problem constants (from setup_inputs) ----------------
constexpr int Mrows = 8192;   // B*S
constexpr int Hdim  = 2048;   // K of main GEMM
constexpr int Sdim  = 4096;
constexpr int HnD   = 4096;   // Hn*D
constexpr int Hn    = 32;
constexpr int Dd    = 128;
constexpr int Lc    = 16384;
constexpr int NFULL = 4352;   // 4096 q + 128 k + 32 w + 96 zero pad (17 tiles of 256)

typedef unsigned short u16;
typedef __attribute__((ext_vector_type(8))) short    bf16x8;
typedef __attribute__((ext_vector_type(4))) float    f32x4;
typedef __attribute__((ext_vector_type(8))) unsigned short u16x8;

__device__ __forceinline__ float bf2f(u16 u) {
    union { unsigned int i; float f; } v; v.i = ((unsigned int)u) << 16; return v.f;
}
__device__ __forceinline__ u16 f2bf(float f) {
    union { float f; unsigned int i; } v; v.f = f;
    unsigned int x = v.i;
    return (u16)((x + 0x7fffu + ((x >> 16) & 1u)) >> 16);   // RNE
}
__device__ __forceinline__ void gload_lds16(const void* g, void* l) {
    __builtin_amdgcn_global_load_lds(
        (const __attribute__((address_space(1))) void*)g,
        (__attribute__((address_space(3))) void*)l, 16, 0, 0);
}

// ------- 1) per-row stats (rms, mu, rstd) + fp32 -> bf16 copy of x -------
__global__ __launch_bounds__(256) void stats_cvt(
    const float* __restrict__ x, u16* __restrict__ xb, float* __restrict__ rms,
    float* __restrict__ mu, float* __restrict__ rstd)
{
    int r = blockIdx.x, t = threadIdx.x;
    const float4* xr = (const float4*)(x + (size_t)r * Hdim);
    float4 a = xr[2 * t], bq = xr[2 * t + 1];
    float v[8] = {a.x, a.y, a.z, a.w, bq.x, bq.y, bq.z, bq.w};
    float s = 0.f, ss = 0.f;
    __align__(16) u16 o[8];
    #pragma unroll
    for (int i = 0; i < 8; i++) { s += v[i]; ss += v[i] * v[i]; o[i] = f2bf(v[i]); }
    ((u16x8*)(xb + (size_t)r * Hdim))[t] = *(const u16x8*)o;
    for (int oo = 32; oo > 0; oo >>= 1) { s += __shfl_down(s, oo); ss += __shfl_down(ss, oo); }
    __shared__ float as[4], ass[4];
    if ((t & 63) == 0) { as[t >> 6] = s; ass[t >> 6] = ss; }
    __syncthreads();
    if (t == 0) {
        float S1 = as[0] + as[1] + as[2] + as[3];
        float S2 = ass[0] + ass[1] + ass[2] + ass[3];
        float mean = S1 / Hdim, msq = S2 / Hdim;
        rms[r]  = rsqrtf(msq + 1e-6f);
        mu[r]   = mean;
        rstd[r] = rsqrtf(msq - mean * mean + 1e-6f);
    }
}

// ---------------- 2) build B'^T = [c1*wqb | g*wk | wproj | 0]^T, [NFULL][H] ---
__global__ __launch_bounds__(256) void prep_wt(
    const float* __restrict__ wqb, const float* __restrict__ qn, const float* __restrict__ qns,
    const float* __restrict__ wk,  const float* __restrict__ g,  const float* __restrict__ wproj,
    u16* __restrict__ wt)
{
    __shared__ u16 tile[64][72];
    int k0 = blockIdx.x * 64, n0 = blockIdx.y * 64;
    int t = threadIdx.x;
    int lk = t >> 2, lc0 = (t & 3) * 16;
    int k = k0 + lk;
    float c1k = qn[k] * qns[k];
    float gk  = g[k];
    #pragma unroll
    for (int i = 0; i < 16; i++) {
        int n = n0 + lc0 + i;
        float val;
        if (n < 4096)      val = wqb[(size_t)k * HnD + n] * c1k;
        else if (n < 4224) val = wk[k * Dd + (n - 4096)] * gk;
        else if (n < 4256) val = wproj[k * Hn + (n - 4224)];
        else               val = 0.f;
        tile[lk][lc0 + i] = f2bf(val);
    }
    __syncthreads();
    int ln = t >> 2, lk0 = (t & 3) * 16;
    __align__(16) u16 o[16];
    #pragma unroll
    for (int i = 0; i < 16; i++) o[i] = tile[lk0 + i][ln];
    u16* dst = wt + (size_t)(n0 + ln) * Hdim + k0 + lk0;
    *(u16x8*)dst = *(const u16x8*)o;
    *(u16x8*)(dst + 8) = *((const u16x8*)o + 1);
}

// ------- 3) transpose hadamard matrices to bf16 (LDS-tiled, coalesced) ----
__global__ __launch_bounds__(256) void transpose_h(
    const float* __restrict__ hq, const float* __restrict__ hk,
    u16* __restrict__ hqt, u16* __restrict__ hkt)
{
    __shared__ float tile[128][129];
    const float* src = blockIdx.x ? hk : hq;
    u16* dst = blockIdx.x ? hkt : hqt;
    int t = threadIdx.x;
    int r = t >> 1, h = (t & 1) * 64;
    #pragma unroll
    for (int j = 0; j < 16; j++) {
        float4 v = *(const float4*)(src + r * Dd + h + 4 * j);
        tile[r][h + 4 * j]     = v.x;
        tile[r][h + 4 * j + 1] = v.y;
        tile[r][h + 4 * j + 2] = v.z;
        tile[r][h + 4 * j + 3] = v.w;
    }
    __syncthreads();
    #pragma unroll
    for (int j0 = 0; j0 < 64; j0 += 8) {
        __align__(16) u16 o[8];
        #pragma unroll
        for (int j = 0; j < 8; j++) o[j] = f2bf(tile[h + j0 + j][r]);
        *(u16x8*)(dst + r * Dd + h + j0) = *(const u16x8*)o;
    }
}

// ---------------- 4) bdot[n]=sum_k b*wk, gdot[n]=sum_k g*wk ------------
__global__ __launch_bounds__(256) void bg_dot(
    const float* __restrict__ wk, const float* __restrict__ g, const float* __restrict__ b,
    float* __restrict__ bdot, float* __restrict__ gdot)
{
    int n = blockIdx.x, t = threadIdx.x;
    float sb = 0.f, sg = 0.f;
    for (int k = t; k < Hdim; k += 256) {
        float w = wk[k * Dd + n];
        sb += b[k] * w;
        sg += g[k] * w;
    }
    for (int o = 32; o > 0; o >>= 1) { sb += __shfl_down(sb, o); sg += __shfl_down(sg, o); }
    __shared__ float rb[4], rg[4];
    if ((t & 63) == 0) { rb[t >> 6] = sb; rg[t >> 6] = sg; }
    __syncthreads();
    if (t == 0) { bdot[n] = rb[0] + rb[1] + rb[2] + rb[3]; gdot[n] = rg[0] + rg[1] + rg[2] + rg[3]; }
}

// ---------------- 5) main fused GEMM, 256x256, counted-vmcnt pipeline -----
// BM=BN=256, BK=64 split into two 32-wide K sub-tiles per buffer; 512 thr
// (8 waves, 4M x 2N: wave owns 64 rows x one 128-col head -> in-register RoPE
// partner nt^4). LDS per buffer: A[kk0]|A[kk1]|B[kk0]|B[kk1], each [256][32]
// bf16 (64 B rows) with 16B-slot XOR swizzle slot = chunk ^ ((row>>1)&3)
// (<=2-way conflicts, free). Prefetch: ph0 of tile t issues ALL of t+1's kk0
// (4 units, 1 load/thread each), ph1 issues t+1's kk1 -> issue->wait gap
// 4-5 phases. Counted waits: vmcnt(8) end-ph1 (waits this tile's kk1),
// vmcnt(4) end-ph3 (waits next tile's kk0). Drain-0 only at t=31.
// Default block mapping (grid 32x17): each XCD gets 4 bm values -> A panels
// L2-resident; no hand swizzle (round-3's bm-sweep doubled FETCH).
#define LDA_(buf, kk, mt) (*(const bf16x8*)(lds + (buf)*65536 + (kk)*16384 + \
    (wr*64 + (mt)*16 + l15) * 64 + qsw))
#define LDB_(buf, kk, nt) (*(const bf16x8*)(lds + (buf)*65536 + 32768 + (kk)*16384 + \
    (wc*128 + (nt)*16 + l15) * 64 + qsw))
#define STG_A(bufb, kk, rh, kt) gload_lds16( \
    Ab + (size_t)((rh)*128 + lrow) * Hdim + (kt)*64 + (kk)*32 + gcol, \
    lds + (bufb)*65536 + (kk)*16384 + (rh)*8192 + wq1024)
#define STG_B(bufb, kk, rh, kt) gload_lds16( \
    Bb + (size_t)((rh)*128 + lrow) * Hdim + (kt)*64 + (kk)*32 + gcol, \
    lds + (bufb)*65536 + 32768 + (kk)*16384 + (rh)*8192 + wq1024)
#define MFMA16(AV, NB) do { \
    _Pragma("unroll") \
    for (int mt = 0; mt < 4; mt++) \
        _Pragma("unroll") \
        for (int nt = 0; nt < 4; nt++) \
            acc[mt][(NB)*4 + nt] = __builtin_amdgcn_mfma_f32_16x16x32_bf16( \
                AV[mt], bfr[nt], acc[mt][(NB)*4 + nt], 0, 0, 0); \
} while (0)

__global__ __launch_bounds__(512, 2) void main_gemm(
    const u16* __restrict__ A, const u16* __restrict__ Bt,
    const float* __restrict__ rms, const float* __restrict__ mu, const float* __restrict__ rstd,
    const float* __restrict__ qbs,
    const float* __restrict__ bdot, const float* __restrict__ gdot,
    const u16* __restrict__ hqt,
    const float* __restrict__ cosr, const float* __restrict__ sinr,
    float* __restrict__ oq, float* __restrict__ oqs,
    float* __restrict__ kpre, float* __restrict__ wout)
{
    __shared__ __align__(16) char lds[131072];

    int tid = threadIdx.x;
    int w = tid >> 6, lane = tid & 63, quad = lane >> 4, l15 = lane & 15;
    int wr = w >> 1, wc = w & 1;                 // 4 M-waves x 2 N-waves
    int bm = blockIdx.x, bn = blockIdx.y;        // default mapping (no swizzle)
    int brow = bm * 256;
    int qsw = (quad ^ ((l15 >> 1) & 3)) * 16;    // read-side 16B-slot swizzle

    const u16* Ab = A  + (size_t)brow * Hdim;
    const u16* Bb = Bt + (size_t)(bn * 256) * Hdim;

    // staging geometry: one load/thread per 8 KB unit (128 rows x 32 cols)
    int lrow = tid >> 2;                         // 0..127
    int gcol = (((tid & 3) ^ ((lrow >> 1) & 3)) * 8);   // pre-swizzled src chunk
    int wq1024 = w * 1024;                       // wave-uniform LDS dest part

    f32x4 acc[4][8] = {};

    // prologue: stage tile 0 (kk0 then kk1) into buf 0
    STG_A(0, 0, 0, 0); STG_A(0, 0, 1, 0); STG_B(0, 0, 0, 0); STG_B(0, 0, 1, 0);
    STG_A(0, 1, 0, 0); STG_A(0, 1, 1, 0); STG_B(0, 1, 0, 0); STG_B(0, 1, 1, 0);
    asm volatile("s_waitcnt vmcnt(4)" ::: "memory");
    __builtin_amdgcn_sched_barrier(0);
    __builtin_amdgcn_s_barrier();

    for (int t = 0; t < 32; t++) {
        int buf = t & 1, nb = buf ^ 1;
        bool pf = (t < 31);
        bf16x8 a0[4], bfr[4];
        // ---- ph0: kk0 A frags + B n0-3; issue t+1 kk0 (4 units) ----
        #pragma unroll
        for (int mt = 0; mt < 4; mt++) a0[mt] = LDA_(buf, 0, mt);
        #pragma unroll
        for (int nt = 0; nt < 4; nt++) bfr[nt] = LDB_(buf, 0, nt);
        if (pf) { STG_A(nb, 0, 0, t+1); STG_A(nb, 0, 1, t+1); STG_B(nb, 0, 0, t+1); STG_B(nb, 0, 1, t+1); }
        asm volatile("s_waitcnt lgkmcnt(0)" ::: "memory");
        __builtin_amdgcn_sched_barrier(0);
        __builtin_amdgcn_s_setprio(1);
        MFMA16(a0, 0);
        __builtin_amdgcn_s_setprio(0);
        __builtin_amdgcn_s_barrier();
        // ---- ph1: kk0 B n4-7; issue t+1 kk1 (4 units); counted wait ----
        #pragma unroll
        for (int nt = 0; nt < 4; nt++) bfr[nt] = LDB_(buf, 0, 4 + nt);
        if (pf) { STG_A(nb, 1, 0, t+1); STG_A(nb, 1, 1, t+1); STG_B(nb, 1, 0, t+1); STG_B(nb, 1, 1, t+1); }
        asm volatile("s_waitcnt lgkmcnt(0)" ::: "memory");
        __builtin_amdgcn_sched_barrier(0);
        __builtin_amdgcn_s_setprio(1);
        MFMA16(a0, 1);
        __builtin_amdgcn_s_setprio(0);
        if (pf) { asm volatile("s_waitcnt vmcnt(8)" ::: "memory"); }
        else    { asm volatile("s_waitcnt vmcnt(0)" ::: "memory"); }
        __builtin_amdgcn_sched_barrier(0);
        __builtin_amdgcn_s_barrier();
        // ---- ph2: kk1 A frags + B n0-3 ----
        #pragma unroll
        for (int mt = 0; mt < 4; mt++) a0[mt] = LDA_(buf, 1, mt);
        #pragma unroll
        for (int nt = 0; nt < 4; nt++) bfr[nt] = LDB_(buf, 1, nt);
        asm volatile("s_waitcnt lgkmcnt(0)" ::: "memory");
        __builtin_amdgcn_sched_barrier(0);
        __builtin_amdgcn_s_setprio(1);
        MFMA16(a0, 0);
        __builtin_amdgcn_s_setprio(0);
        __builtin_amdgcn_s_barrier();
        // ---- ph3: kk1 B n4-7; counted wait for t+1 kk0 ----
        #pragma unroll
        for (int nt = 0; nt < 4; nt++) bfr[nt] = LDB_(buf, 1, 4 + nt);
        asm volatile("s_waitcnt lgkmcnt(0)" ::: "memory");
        __builtin_amdgcn_sched_barrier(0);
        __builtin_amdgcn_s_setprio(1);
        MFMA16(a0, 1);
        __builtin_amdgcn_s_setprio(0);
        asm volatile("s_waitcnt vmcnt(4)" ::: "memory");
        __builtin_amdgcn_sched_barrier(0);
        __builtin_amdgcn_s_barrier();
    }

    if (bn < 16) {
        // -------- fused q epilogue: scale -> RoPE -> P (per-wave LDS, swizzled)
        //          -> hadamard MFMA -> absmax -> quant -> store
        __syncthreads();
        int head = bn * 2 + wc;                  // 0..31
        char* Pw = lds + w * 16384;              // per-wave [64][256B] region
        float qb[8];
        #pragma unroll
        for (int nt = 0; nt < 8; nt++) qb[nt] = qbs[head * 128 + nt * 16 + l15];
        #pragma unroll
        for (int mt = 0; mt < 4; mt++) {
            float y[8][4];
            #pragma unroll
            for (int reg = 0; reg < 4; reg++) {
                float rv = rms[brow + wr * 64 + mt * 16 + quad * 4 + reg];
                #pragma unroll
                for (int nt = 0; nt < 8; nt++) y[nt][reg] = acc[mt][nt][reg] * rv * qb[nt];
            }
            #pragma unroll
            for (int reg = 0; reg < 4; reg++) {
                int rp = mt * 16 + quad * 4 + reg;          // 0..63 local row
                int s_ = (brow + wr * 64 + rp) & (Sdim - 1);
                const float* cr = cosr + (size_t)s_ * Dd + l15;
                const float* sr = sinr + (size_t)s_ * Dd + l15;
                int sw = (rp & 7) << 4;
                #pragma unroll
                for (int nt = 0; nt < 8; nt++) {
                    float c  = cr[nt * 16];
                    float sv = sr[nt * 16];
                    float sign = (nt < 4) ? -1.f : 1.f;
                    float o = y[nt][reg] * c + sign * y[nt ^ 4][reg] * sv;   // fp32 RoPE
                    int colb = (nt * 16 + l15) * 2;
                    *(u16*)(Pw + rp * 256 + (colb ^ sw)) = f2bf(o);
                }
            }
        }
        __syncthreads();
        #pragma unroll
        for (int mt = 0; mt < 4; mt++) {
            bf16x8 pa[4];
            #pragma unroll
            for (int kb = 0; kb < 4; kb++) {
                int row = mt * 16 + l15;
                pa[kb] = *(const bf16x8*)(Pw + row * 256 + ((kb * 64 + quad * 16) ^ ((row & 7) << 4)));
            }
            f32x4 a2[8] = {};
            #pragma unroll
            for (int nt = 0; nt < 8; nt++) {
                #pragma unroll
                for (int kb = 0; kb < 4; kb++) {
                    bf16x8 hb = *(const bf16x8*)(hqt + (size_t)(nt * 16 + l15) * Dd + kb * 32 + quad * 8);
                    a2[nt] = __builtin_amdgcn_mfma_f32_16x16x32_bf16(pa[kb], hb, a2[nt], 0, 0, 0);
                }
            }
            #pragma unroll
            for (int reg = 0; reg < 4; reg++) {
                float m = 0.f;
                #pragma unroll
                for (int nt = 0; nt < 8; nt++) m = fmaxf(m, fabsf(a2[nt][reg]));
                m = fmaxf(m, __shfl_xor(m, 8));
                m = fmaxf(m, __shfl_xor(m, 4));
                m = fmaxf(m, __shfl_xor(m, 2));
                m = fmaxf(m, __shfl_xor(m, 1));
                float scale = fmaxf(m * (1.f / 127.f), 1e-8f);
                float inv = 1.f / scale;
                int r = brow + wr * 64 + mt * 16 + quad * 4 + reg;
                float* orow = oq + (size_t)r * HnD + head * 128;
                #pragma unroll
                for (int nt = 0; nt < 8; nt++)
                    orow[nt * 16 + l15] = rintf(a2[nt][reg] * inv);
                if (l15 == 0) oqs[(size_t)r * Hn + head] = scale;
            }
        }
    } else {                       // bn == 16: wc==0 -> k cols, wc==1 -> w cols
        if (wc == 0) {
            float bd[8], gd[8];
            #pragma unroll
            for (int nt = 0; nt < 8; nt++) { bd[nt] = bdot[nt * 16 + l15]; gd[nt] = gdot[nt * 16 + l15]; }
            #pragma unroll
            for (int mt = 0; mt < 4; mt++)
                #pragma unroll
                for (int reg = 0; reg < 4; reg++) {
                    int r = brow + wr * 64 + mt * 16 + quad * 4 + reg;
                    float sd = rstd[r], m_ = mu[r];
                    #pragma unroll
                    for (int nt = 0; nt < 8; nt++)
                        kpre[(size_t)r * Dd + nt * 16 + l15] = acc[mt][nt][reg] * sd + bd[nt] - sd * m_ * gd[nt];
                }
        } else {
            #pragma unroll
            for (int mt = 0; mt < 4; mt++)
                #pragma unroll
                for (int reg = 0; reg < 4; reg++) {
                    int r = brow + wr * 64 + mt * 16 + quad * 4 + reg;
                    #pragma unroll
                    for (int nt = 0; nt < 2; nt++)       // n = nt*16+l15 in 0..31
                        wout[(size_t)r * Hn + nt * 16 + l15] = acc[mt][nt][reg];
                }
        }
    }
}

// ---------------- 6) copy cache defaults into outputs (fp32) -------------
__global__ void copy_cache(const float* __restrict__ kc, const float* __restrict__ kcs,
                           float* __restrict__ dk, float* __restrict__ dks)
{
    int g = blockIdx.x * 256 + threadIdx.x;          // 262144 threads, 8 floats each
    ((float4*)dk)[2 * g]     = ((const float4*)kc)[2 * g];
    ((float4*)dk)[2 * g + 1] = ((const float4*)kc)[2 * g + 1];
    if (g < Lc / 8) {
        ((float4*)dks)[2 * g]     = ((const float4*)kcs)[2 * g];
        ((float4*)dks)[2 * g + 1] = ((const float4*)kcs)[2 * g + 1];
    }
}

// ---------------- 7) K-branch: RoPE + Hadamard (MFMA) + quant + scatter ----
template <int IS_K>
__global__ __launch_bounds__(256) void post_kernel(
    const float* src,               // k: [M][128] (fp32)
    const u16* __restrict__ ht,     // transposed hadamard [n][k] bf16
    const float* __restrict__ cosr, const float* __restrict__ sinr,  // [S][128] fp32
    const int* __restrict__ idx,    // k only
    float* dstq, float* __restrict__ dsts)
{
    constexpr int RP = 136;  // padded LDS row stride (elements)
    __shared__ __align__(16) u16 sA[32 * RP];
    __shared__ __align__(16) u16 sB[128 * RP];
    __shared__ float pamax[32][2];
    __shared__ int sidx[32];

    int blk = blockIdx.x, tid = threadIdx.x;

    { // stage hadamard^T into padded LDS
        int n = tid >> 1, kk0 = (tid & 1) * 64;
        const u16x8* gp = (const u16x8*)(ht + n * Dd + kk0);
        u16* lb = sB + n * RP + kk0;
        #pragma unroll
        for (int j = 0; j < 8; j++) *(u16x8*)(lb + j * 8) = gp[j];
    }
    { // stage 32 rows with RoPE applied (fp32 reads -> bf16 LDS)
        int r = tid >> 3, c = tid & 7;
        int d0 = c * 16;
        int s_ = IS_K ? ((blk * 32 + r) & (Sdim - 1)) : (blk & (Sdim - 1));
        const float* srow = src + (size_t)blk * 4096 + r * Dd;
        int p0 = (d0 + 64) & 127;
        float sign = (d0 < 64) ? -1.f : 1.f;
        float vv[16], pv[16], cv[16], sv[16];
        #pragma unroll
        for (int j = 0; j < 4; j++) {
            float4 a = *(const float4*)(srow + d0 + 4 * j);
            float4 p = *(const float4*)(srow + p0 + 4 * j);
            float4 cc = *(const float4*)(cosr + (size_t)s_ * Dd + d0 + 4 * j);
            float4 sc = *(const float4*)(sinr + (size_t)s_ * Dd + d0 + 4 * j);
            vv[4*j] = a.x; vv[4*j+1] = a.y; vv[4*j+2] = a.z; vv[4*j+3] = a.w;
            pv[4*j] = p.x; pv[4*j+1] = p.y; pv[4*j+2] = p.z; pv[4*j+3] = p.w;
            cv[4*j] = cc.x; cv[4*j+1] = cc.y; cv[4*j+2] = cc.z; cv[4*j+3] = cc.w;
            sv[4*j] = sc.x; sv[4*j+1] = sc.y; sv[4*j+2] = sc.z; sv[4*j+3] = sc.w;
        }
        __align__(16) u16 o[16];
        #pragma unroll
        for (int i = 0; i < 16; i++)
            o[i] = f2bf(vv[i] * cv[i] + sign * pv[i] * sv[i]);
        u16* la = sA + r * RP + d0;
        *(u16x8*)la = *(const u16x8*)o;
        *(u16x8*)(la + 8) = *((const u16x8*)o + 1);
        if (IS_K && tid < 32) sidx[tid] = idx[blk * 32 + tid];
    }
    __syncthreads();

    int w = tid >> 6, lane = tid & 63, quad = lane >> 4, l15 = lane & 15;
    int rs = (w & 1) * 16, cg = (w >> 1) * 64;
    f32x4 acc[4] = {};
    #pragma unroll
    for (int kb = 0; kb < 4; kb++) {
        bf16x8 a = *(const bf16x8*)(sA + (rs + l15) * RP + kb * 32 + quad * 8);
        #pragma unroll
        for (int nt = 0; nt < 4; nt++) {
            bf16x8 b = *(const bf16x8*)(sB + (cg + nt * 16 + l15) * RP + kb * 32 + quad * 8);
            acc[nt] = __builtin_amdgcn_mfma_f32_16x16x32_bf16(a, b, acc[nt], 0, 0, 0);
        }
    }
    #pragma unroll
    for (int reg = 0; reg < 4; reg++) {
        float m = 0.f;
        #pragma unroll
        for (int nt = 0; nt < 4; nt++) m = fmaxf(m, fabsf(acc[nt][reg]));
        m = fmaxf(m, __shfl_xor(m, 8));
        m = fmaxf(m, __shfl_xor(m, 4));
        m = fmaxf(m, __shfl_xor(m, 2));
        m = fmaxf(m, __shfl_xor(m, 1));
        if (l15 == 0) pamax[rs + quad * 4 + reg][w >> 1] = m;
    }
    __syncthreads();
    #pragma unroll
    for (int reg = 0; reg < 4; reg++) {
        int r = rs + quad * 4 + reg;
        float am = fmaxf(pamax[r][0], pamax[r][1]);
        float scale = fmaxf(am * (1.f / 127.f), 1e-8f);
        float inv = 1.f / scale;
        size_t dro = IS_K ? (size_t)sidx[r] * Dd : (size_t)blk * 4096 + (size_t)r * Dd;
        #pragma unroll
        for (int nt = 0; nt < 4; nt++)
            dstq[dro + cg + nt * 16 + l15] = rintf(acc[nt][reg] * inv);
        if (l15 == 0 && (w >> 1) == 0)
            dsts[IS_K ? sidx[r] : blk * Hn + r] = scale;
    }
}

// ---------------- launch ------------------------------------------------
extern "C" void kernel_launch(void* const* d_in, const int* in_sizes, int n_in,
                              void* d_out, int out_size, void* d_ws, size_t ws_size,
                              hipStream_t stream) {
    (void)in_sizes; (void)n_in; (void)out_size; (void)ws_size;
    const float* x    = (const float*)d_in[0];
    const float* qn   = (const float*)d_in[1];
    const float* qns  = (const float*)d_in[2];
    const float* wqb  = (const float*)d_in[3];
    const float* wqbs = (const float*)d_in[4];
    const float* wk   = (const float*)d_in[5];
    const float* wpj  = (const float*)d_in[6];
    const float* g    = (const float*)d_in[7];
    const float* b    = (const float*)d_in[8];
    const float* cosr = (const float*)d_in[9];
    const float* sinr = (const float*)d_in[10];
    const float* hq   = (const float*)d_in[11];
    const float* hk   = (const float*)d_in[12];
    const float* kc   = (const float*)d_in[13];
    const float* kcs  = (const float*)d_in[14];
    const int*   idx  = (const int*)d_in[15];

    // ws layout
    char* ws = (char*)d_ws;
    size_t o = 0;
    u16* xb  = (u16*)(ws + o); o += (size_t)Mrows * Hdim * 2;   // 33.55 MB
    u16* wt  = (u16*)(ws + o); o += (size_t)NFULL * Hdim * 2;   // 17.83 MB
    u16* hqt = (u16*)(ws + o); o += Dd * Dd * 2;
    u16* hkt = (u16*)(ws + o); o += Dd * Dd * 2;
    float* rmsb  = (float*)(ws + o); o += (size_t)Mrows * 4;
    float* mub   = (float*)(ws + o); o += (size_t)Mrows * 4;
    float* rstdb = (float*)(ws + o); o += (size_t)Mrows * 4;
    float* bdotb = (float*)(ws + o); o += 512;
    float* gdotb = (float*)(ws + o); o += 512;
    float* kpre  = (float*)(ws + o); o += (size_t)Mrows * Dd * 4;  // 4.19 MB

    float* out = (float*)d_out;
    float* oq  = out;                             // [M][4096]
    float* oqs = oq  + (size_t)Mrows * HnD;       // [M][32]
    float* ok  = oqs + (size_t)Mrows * Hn;        // [L][128]
    float* oks = ok  + (size_t)Lc * Dd;           // [L]
    float* ow  = oks + Lc;                        // [M][32]

    stats_cvt<<<Mrows, 256, 0, stream>>>(x, xb, rmsb, mub, rstdb);
    prep_wt<<<dim3(Hdim / 64, NFULL / 64), 256, 0, stream>>>(wqb, qn, qns, wk, g, wpj, wt);
    transpose_h<<<2, 256, 0, stream>>>(hq, hk, hqt, hkt);
    bg_dot<<<Dd, 256, 0, stream>>>(wk, g, b, bdotb, gdotb);
    main_gemm<<<dim3(32, 17), 512, 0, stream>>>(
        xb, wt, rmsb, mub, rstdb, wqbs, bdotb, gdotb, hqt, cosr, sinr, oq, oqs, kpre, ow);
    copy_cache<<<(Lc * Dd / 8) / 256, 256, 0, stream>>>(kc, kcs, ok, oks);
    post_kernel<1><<<Mrows / 32, 256, 0, stream>>>(kpre, hkt, cosr, sinr, idx, ok, oks);
}

// Round 5
// 496.878 us; speedup vs baseline: 1.1626x; 1.0230x over previous
//
#include <hip/hip_runtime.h>
#include <hip/hip_bf16.h>
#include <stdint.h>

// ---------------- problem constants (from setup_inputs) ----------------
constexpr int Mrows = 8192;   // B*S
constexpr int Hdim  = 2048;   // K of main GEMM
constexpr int Sdim  = 4096;
constexpr int HnD   = 4096;   // Hn*D
constexpr int Hn    = 32;
constexpr int Dd    = 128;
constexpr int Lc    = 16384;
constexpr int NFULL = 4352;   // staged B' rows: 4096 q + 128 k + 32 w + 96 zero pad

typedef unsigned short u16;
typedef __attribute__((ext_vector_type(8))) short    bf16x8;
typedef __attribute__((ext_vector_type(4))) float    f32x4;
typedef __attribute__((ext_vector_type(8))) unsigned short u16x8;

__device__ __forceinline__ float bf2f(u16 u) {
    union { unsigned int i; float f; } v; v.i = ((unsigned int)u) << 16; return v.f;
}
__device__ __forceinline__ u16 f2bf(float f) {
    union { float f; unsigned int i; } v; v.f = f;
    unsigned int x = v.i;
    return (u16)((x + 0x7fffu + ((x >> 16) & 1u)) >> 16);   // RNE
}
__device__ __forceinline__ void gload_lds16(const void* g, void* l) {
    __builtin_amdgcn_global_load_lds(
        (const __attribute__((address_space(1))) void*)g,
        (__attribute__((address_space(3))) void*)l, 16, 0, 0);
}

// ------- 1) per-row stats (rms, mu, rstd) + fp32 -> bf16 copy of x -------
__global__ __launch_bounds__(256) void stats_cvt(
    const float* __restrict__ x, u16* __restrict__ xb, float* __restrict__ rms,
    float* __restrict__ mu, float* __restrict__ rstd)
{
    int r = blockIdx.x, t = threadIdx.x;
    const float4* xr = (const float4*)(x + (size_t)r * Hdim);
    float4 a = xr[2 * t], bq = xr[2 * t + 1];
    float v[8] = {a.x, a.y, a.z, a.w, bq.x, bq.y, bq.z, bq.w};
    float s = 0.f, ss = 0.f;
    __align__(16) u16 o[8];
    #pragma unroll
    for (int i = 0; i < 8; i++) { s += v[i]; ss += v[i] * v[i]; o[i] = f2bf(v[i]); }
    ((u16x8*)(xb + (size_t)r * Hdim))[t] = *(const u16x8*)o;
    for (int oo = 32; oo > 0; oo >>= 1) { s += __shfl_down(s, oo); ss += __shfl_down(ss, oo); }
    __shared__ float as[4], ass[4];
    if ((t & 63) == 0) { as[t >> 6] = s; ass[t >> 6] = ss; }
    __syncthreads();
    if (t == 0) {
        float S1 = as[0] + as[1] + as[2] + as[3];
        float S2 = ass[0] + ass[1] + ass[2] + ass[3];
        float mean = S1 / Hdim, msq = S2 / Hdim;
        rms[r]  = rsqrtf(msq + 1e-6f);
        mu[r]   = mean;
        rstd[r] = rsqrtf(msq - mean * mean + 1e-6f);
    }
}

// ---------------- 2) build B'^T = [c1*wqb | g*wk | wproj | 0]^T, [NFULL][H] ---
__global__ __launch_bounds__(256) void prep_wt(
    const float* __restrict__ wqb, const float* __restrict__ qn, const float* __restrict__ qns,
    const float* __restrict__ wk,  const float* __restrict__ g,  const float* __restrict__ wproj,
    u16* __restrict__ wt)
{
    __shared__ u16 tile[64][72];
    int k0 = blockIdx.x * 64, n0 = blockIdx.y * 64;
    int t = threadIdx.x;
    int lk = t >> 2, lc0 = (t & 3) * 16;
    int k = k0 + lk;
    float c1k = qn[k] * qns[k];
    float gk  = g[k];
    #pragma unroll
    for (int i = 0; i < 16; i++) {
        int n = n0 + lc0 + i;
        float val;
        if (n < 4096)      val = wqb[(size_t)k * HnD + n] * c1k;
        else if (n < 4224) val = wk[k * Dd + (n - 4096)] * gk;
        else if (n < 4256) val = wproj[k * Hn + (n - 4224)];
        else               val = 0.f;
        tile[lk][lc0 + i] = f2bf(val);
    }
    __syncthreads();
    int ln = t >> 2, lk0 = (t & 3) * 16;
    __align__(16) u16 o[16];
    #pragma unroll
    for (int i = 0; i < 16; i++) o[i] = tile[lk0 + i][ln];
    u16* dst = wt + (size_t)(n0 + ln) * Hdim + k0 + lk0;
    *(u16x8*)dst = *(const u16x8*)o;
    *(u16x8*)(dst + 8) = *((const u16x8*)o + 1);
}

// ------- 3) transpose hadamard matrices to bf16 (LDS-tiled, coalesced) ----
__global__ __launch_bounds__(256) void transpose_h(
    const float* __restrict__ hq, const float* __restrict__ hk,
    u16* __restrict__ hqt, u16* __restrict__ hkt)
{
    __shared__ float tile[128][129];
    const float* src = blockIdx.x ? hk : hq;
    u16* dst = blockIdx.x ? hkt : hqt;
    int t = threadIdx.x;
    int r = t >> 1, h = (t & 1) * 64;
    #pragma unroll
    for (int j = 0; j < 16; j++) {
        float4 v = *(const float4*)(src + r * Dd + h + 4 * j);
        tile[r][h + 4 * j]     = v.x;
        tile[r][h + 4 * j + 1] = v.y;
        tile[r][h + 4 * j + 2] = v.z;
        tile[r][h + 4 * j + 3] = v.w;
    }
    __syncthreads();
    #pragma unroll
    for (int j0 = 0; j0 < 64; j0 += 8) {
        __align__(16) u16 o[8];
        #pragma unroll
        for (int j = 0; j < 8; j++) o[j] = f2bf(tile[h + j0 + j][r]);
        *(u16x8*)(dst + r * Dd + h + j0) = *(const u16x8*)o;
    }
}

// ---------------- 4) bdot[n]=sum_k b*wk, gdot[n]=sum_k g*wk ------------
__global__ __launch_bounds__(256) void bg_dot(
    const float* __restrict__ wk, const float* __restrict__ g, const float* __restrict__ b,
    float* __restrict__ bdot, float* __restrict__ gdot)
{
    int n = blockIdx.x, t = threadIdx.x;
    float sb = 0.f, sg = 0.f;
    for (int k = t; k < Hdim; k += 256) {
        float w = wk[k * Dd + n];
        sb += b[k] * w;
        sg += g[k] * w;
    }
    for (int o = 32; o > 0; o >>= 1) { sb += __shfl_down(sb, o); sg += __shfl_down(sg, o); }
    __shared__ float rb[4], rg[4];
    if ((t & 63) == 0) { rb[t >> 6] = sb; rg[t >> 6] = sg; }
    __syncthreads();
    if (t == 0) { bdot[n] = rb[0] + rb[1] + rb[2] + rb[3]; gdot[n] = rg[0] + rg[1] + rg[2] + rg[3]; }
}

// ---------------- 5) main fused q-GEMM: 128x256 tile, 2 blocks/CU ---------
// 256 thr = 4 waves (2M x 2N): wave owns 64 rows x one 128-col head ->
// in-register RoPE partner nt^4. BK=32, TRIPLE-buffered LDS (3 x 24KB = 72KB)
// -> 2 independent blocks/CU whose read-windows and MFMA-windows overlap
// (breaks round-4's single-block lockstep serialization). Counted vmcnt:
// stage slot s+2 during step s, wait vmcnt(6) per step (drain s+1), drain-0
// only at s>=62. One barrier per step. 16B-slot XOR swizzle both-sides.
// Grid 64x16 = 1024 blocks = exactly 2 gens of 512 -> zero tail (k/w columns
// moved to kw_gemm).
#define QLDA(slotb, mt) (*(const bf16x8*)(lds + (slotb) + \
    (wr*64 + (mt)*16 + l15) * 64 + qsw))
#define QLDB(slotb, nt) (*(const bf16x8*)(lds + (slotb) + 8192 + \
    (wc*128 + (nt)*16 + l15) * 64 + qsw))
#define QSTG(slotb, sidx) do { \
    gload_lds16(Ab + (size_t)(arow)       * Hdim + (sidx) * 32 + acol, lds + (slotb) + wq); \
    gload_lds16(Ab + (size_t)(64 + arow)  * Hdim + (sidx) * 32 + acol, lds + (slotb) + 4096 + wq); \
    gload_lds16(Bb + (size_t)(arow)       * Hdim + (sidx) * 32 + acol, lds + (slotb) + 8192 + wq); \
    gload_lds16(Bb + (size_t)(64 + arow)  * Hdim + (sidx) * 32 + acol, lds + (slotb) + 12288 + wq); \
    gload_lds16(Bb + (size_t)(128 + arow) * Hdim + (sidx) * 32 + acol, lds + (slotb) + 16384 + wq); \
    gload_lds16(Bb + (size_t)(192 + arow) * Hdim + (sidx) * 32 + acol, lds + (slotb) + 20480 + wq); \
} while (0)

__global__ __launch_bounds__(256, 2) void main_gemm(
    const u16* __restrict__ A, const u16* __restrict__ Bt,
    const float* __restrict__ rms, const float* __restrict__ qbs,
    const u16* __restrict__ hqt,
    const float* __restrict__ cosr, const float* __restrict__ sinr,
    float* __restrict__ oq, float* __restrict__ oqs)
{
    __shared__ __align__(16) char lds[73728];    // 3 slots x (A 8KB + B 16KB)

    int tid = threadIdx.x;
    int w = tid >> 6, lane = tid & 63, quad = lane >> 4, l15 = lane & 15;
    int wr = w >> 1, wc = w & 1;                 // 2 M-waves x 2 N-waves
    int bm = blockIdx.x, bn = blockIdx.y;
    int brow = bm * 128;
    int qsw = (quad ^ ((l15 >> 1) & 3)) * 16;    // read-side 16B-slot swizzle

    const u16* Ab = A  + (size_t)brow * Hdim;
    const u16* Bb = Bt + (size_t)(bn * 256) * Hdim;

    // staging geometry: 6 loads/thread/step; source chunk pre-swizzled
    int arow = tid >> 2;                         // 0..63 (row within 64-row unit)
    int acol = (((tid & 3) ^ ((tid >> 3) & 3)) * 8);
    int wq   = w * 1024;                         // wave-uniform LDS dest part

    f32x4 acc[4][8] = {};

    // prologue: stage steps 0,1 into slots 0,1
    QSTG(0, 0);
    QSTG(24576, 1);
    asm volatile("s_waitcnt vmcnt(6)" ::: "memory");
    __builtin_amdgcn_sched_barrier(0);
    __builtin_amdgcn_s_barrier();

    int slotb = 0;                               // slot byte offset of step s
    for (int s = 0; s < 64; s++) {
        bf16x8 af[4], bq[8];
        #pragma unroll
        for (int mt = 0; mt < 4; mt++) af[mt] = QLDA(slotb, mt);
        #pragma unroll
        for (int nt = 0; nt < 8; nt++) bq[nt] = QLDB(slotb, nt);
        if (s + 2 < 64) {
            int ns = slotb + 49152; if (ns >= 73728) ns -= 73728;   // (s+2)%3 slot
            QSTG(ns, s + 2);
        }
        asm volatile("s_waitcnt lgkmcnt(0)" ::: "memory");
        __builtin_amdgcn_sched_barrier(0);
        __builtin_amdgcn_s_setprio(1);
        #pragma unroll
        for (int mt = 0; mt < 4; mt++)
            #pragma unroll
            for (int nt = 0; nt < 8; nt++)
                acc[mt][nt] = __builtin_amdgcn_mfma_f32_16x16x32_bf16(af[mt], bq[nt], acc[mt][nt], 0, 0, 0);
        __builtin_amdgcn_s_setprio(0);
        if (s < 62) { asm volatile("s_waitcnt vmcnt(6)" ::: "memory"); }
        else        { asm volatile("s_waitcnt vmcnt(0)" ::: "memory"); }
        __builtin_amdgcn_sched_barrier(0);
        __builtin_amdgcn_s_barrier();
        slotb += 24576; if (slotb >= 73728) slotb -= 73728;
    }

    // -------- fused q epilogue: scale -> RoPE -> P (per-wave LDS, swizzled)
    //          -> hadamard MFMA -> absmax -> quant -> store
    __syncthreads();
    int head = bn * 2 + wc;                      // 0..31
    char* Pw = lds + w * 16384;                  // per-wave [64][256B] region
    float qb[8];
    #pragma unroll
    for (int nt = 0; nt < 8; nt++) qb[nt] = qbs[head * 128 + nt * 16 + l15];
    #pragma unroll
    for (int mt = 0; mt < 4; mt++) {
        float y[8][4];
        #pragma unroll
        for (int reg = 0; reg < 4; reg++) {
            float rv = rms[brow + wr * 64 + mt * 16 + quad * 4 + reg];
            #pragma unroll
            for (int nt = 0; nt < 8; nt++) y[nt][reg] = acc[mt][nt][reg] * rv * qb[nt];
        }
        #pragma unroll
        for (int reg = 0; reg < 4; reg++) {
            int rp = mt * 16 + quad * 4 + reg;          // 0..63 local row
            int s_ = (brow + wr * 64 + rp) & (Sdim - 1);
            const float* cr = cosr + (size_t)s_ * Dd + l15;
            const float* sr = sinr + (size_t)s_ * Dd + l15;
            int sw = (rp & 7) << 4;
            #pragma unroll
            for (int nt = 0; nt < 8; nt++) {
                float c  = cr[nt * 16];
                float sv = sr[nt * 16];
                float sign = (nt < 4) ? -1.f : 1.f;
                float o = y[nt][reg] * c + sign * y[nt ^ 4][reg] * sv;   // fp32 RoPE
                int colb = (nt * 16 + l15) * 2;
                *(u16*)(Pw + rp * 256 + (colb ^ sw)) = f2bf(o);
            }
        }
    }
    __syncthreads();
    #pragma unroll
    for (int mt = 0; mt < 4; mt++) {
        bf16x8 pa[4];
        #pragma unroll
        for (int kb = 0; kb < 4; kb++) {
            int row = mt * 16 + l15;
            pa[kb] = *(const bf16x8*)(Pw + row * 256 + ((kb * 64 + quad * 16) ^ ((row & 7) << 4)));
        }
        f32x4 a2[8] = {};
        #pragma unroll
        for (int nt = 0; nt < 8; nt++) {
            #pragma unroll
            for (int kb = 0; kb < 4; kb++) {
                bf16x8 hb = *(const bf16x8*)(hqt + (size_t)(nt * 16 + l15) * Dd + kb * 32 + quad * 8);
                a2[nt] = __builtin_amdgcn_mfma_f32_16x16x32_bf16(pa[kb], hb, a2[nt], 0, 0, 0);
            }
        }
        #pragma unroll
        for (int reg = 0; reg < 4; reg++) {
            float m = 0.f;
            #pragma unroll
            for (int nt = 0; nt < 8; nt++) m = fmaxf(m, fabsf(a2[nt][reg]));
            m = fmaxf(m, __shfl_xor(m, 8));
            m = fmaxf(m, __shfl_xor(m, 4));
            m = fmaxf(m, __shfl_xor(m, 2));
            m = fmaxf(m, __shfl_xor(m, 1));
            float scale = fmaxf(m * (1.f / 127.f), 1e-8f);
            float inv = 1.f / scale;
            int r = brow + wr * 64 + mt * 16 + quad * 4 + reg;
            float* orow = oq + (size_t)r * HnD + head * 128;
            #pragma unroll
            for (int nt = 0; nt < 8; nt++)
                orow[nt * 16 + l15] = rintf(a2[nt][reg] * inv);
            if (l15 == 0) oqs[(size_t)r * Hn + head] = scale;
        }
    }
}

// ---------------- 5b) kw-GEMM: cols 4096..4287 of B' (k 128 + w 32 + pad) --
// M=8192, N=192, K=2048. grid 256 (BM=32), 256 thr = 4 waves; wave owns
// 3 col-frags f = w*3+j. Single-buffer LDS, __syncthreads drains vmcnt.
__global__ __launch_bounds__(256) void kw_gemm(
    const u16* __restrict__ A, const u16* __restrict__ Bt,
    const float* __restrict__ rstd, const float* __restrict__ mu,
    const float* __restrict__ bdot, const float* __restrict__ gdot,
    float* __restrict__ kpre, float* __restrict__ wout)
{
    __shared__ __align__(16) u16 sA[32 * 64];    // [32][64] elem, chunk-swizzled
    __shared__ __align__(16) u16 sB[192 * 64];
    int tid = threadIdx.x, w = tid >> 6, lane = tid & 63, quad = lane >> 4, l15 = lane & 15;
    int blk = blockIdx.x;
    const u16* Ab = A  + (size_t)(blk * 32) * Hdim;
    const u16* Bb = Bt + (size_t)4096 * Hdim;

    f32x4 acc[2][3] = {};

    for (int s = 0; s < 32; s++) {
        __syncthreads();                          // readers of prev step done
        {   // stage A: 1 load/thread; row = tid>>3, chunk = tid&7 (pre-swizzled)
            int row = tid >> 3, ch = (tid & 7) ^ (row & 7);
            gload_lds16(Ab + (size_t)row * Hdim + s * 64 + ch * 8, (char*)sA + w * 1024);
        }
        #pragma unroll
        for (int u = 0; u < 6; u++) {             // stage B: 6 loads/thread
            int idx = u * 256 + tid;
            int row = idx >> 3, ch = (idx & 7) ^ (row & 7);
            gload_lds16(Bb + (size_t)row * Hdim + s * 64 + ch * 8,
                        (char*)sB + u * 4096 + w * 1024);
        }
        __syncthreads();                          // drains vmcnt -> data landed
        #pragma unroll
        for (int kk = 0; kk < 2; kk++) {
            bf16x8 af[2], bf[3];
            #pragma unroll
            for (int m = 0; m < 2; m++) {
                int row = m * 16 + l15;
                af[m] = *(const bf16x8*)(sA + row * 64 + (((kk * 4 + quad) ^ (row & 7)) * 8));
            }
            #pragma unroll
            for (int j = 0; j < 3; j++) {
                int row = (w * 3 + j) * 16 + l15;
                bf[j] = *(const bf16x8*)(sB + row * 64 + (((kk * 4 + quad) ^ (row & 7)) * 8));
            }
            #pragma unroll
            for (int m = 0; m < 2; m++)
                #pragma unroll
                for (int j = 0; j < 3; j++)
                    acc[m][j] = __builtin_amdgcn_mfma_f32_16x16x32_bf16(af[m], bf[j], acc[m][j], 0, 0, 0);
        }
    }
    #pragma unroll
    for (int m = 0; m < 2; m++)
        #pragma unroll
        for (int reg = 0; reg < 4; reg++) {
            int r = blk * 32 + m * 16 + quad * 4 + reg;
            float sd = rstd[r], m_ = mu[r];
            #pragma unroll
            for (int j = 0; j < 3; j++) {
                int f = w * 3 + j, c = f * 16 + l15;
                float v = acc[m][j][reg];
                if (f < 8)       kpre[(size_t)r * Dd + c] = v * sd + bdot[c] - sd * m_ * gdot[c];
                else if (f < 10) wout[(size_t)r * Hn + (c - 128)] = v;
            }
        }
}

// ---------------- 6) copy cache defaults into outputs (fp32) -------------
__global__ void copy_cache(const float* __restrict__ kc, const float* __restrict__ kcs,
                           float* __restrict__ dk, float* __restrict__ dks)
{
    int g = blockIdx.x * 256 + threadIdx.x;          // 262144 threads, 8 floats each
    ((float4*)dk)[2 * g]     = ((const float4*)kc)[2 * g];
    ((float4*)dk)[2 * g + 1] = ((const float4*)kc)[2 * g + 1];
    if (g < Lc / 8) {
        ((float4*)dks)[2 * g]     = ((const float4*)kcs)[2 * g];
        ((float4*)dks)[2 * g + 1] = ((const float4*)kcs)[2 * g + 1];
    }
}

// ---------------- 7) K-branch: RoPE + Hadamard (MFMA) + quant + scatter ----
template <int IS_K>
__global__ __launch_bounds__(256) void post_kernel(
    const float* src,               // k: [M][128] (fp32)
    const u16* __restrict__ ht,     // transposed hadamard [n][k] bf16
    const float* __restrict__ cosr, const float* __restrict__ sinr,  // [S][128] fp32
    const int* __restrict__ idx,    // k only
    float* dstq, float* __restrict__ dsts)
{
    constexpr int RP = 136;  // padded LDS row stride (elements)
    __shared__ __align__(16) u16 sA[32 * RP];
    __shared__ __align__(16) u16 sB[128 * RP];
    __shared__ float pamax[32][2];
    __shared__ int sidx[32];

    int blk = blockIdx.x, tid = threadIdx.x;

    { // stage hadamard^T into padded LDS
        int n = tid >> 1, kk0 = (tid & 1) * 64;
        const u16x8* gp = (const u16x8*)(ht + n * Dd + kk0);
        u16* lb = sB + n * RP + kk0;
        #pragma unroll
        for (int j = 0; j < 8; j++) *(u16x8*)(lb + j * 8) = gp[j];
    }
    { // stage 32 rows with RoPE applied (fp32 reads -> bf16 LDS)
        int r = tid >> 3, c = tid & 7;
        int d0 = c * 16;
        int s_ = IS_K ? ((blk * 32 + r) & (Sdim - 1)) : (blk & (Sdim - 1));
        const float* srow = src + (size_t)blk * 4096 + r * Dd;
        int p0 = (d0 + 64) & 127;
        float sign = (d0 < 64) ? -1.f : 1.f;
        float vv[16], pv[16], cv[16], sv[16];
        #pragma unroll
        for (int j = 0; j < 4; j++) {
            float4 a = *(const float4*)(srow + d0 + 4 * j);
            float4 p = *(const float4*)(srow + p0 + 4 * j);
            float4 cc = *(const float4*)(cosr + (size_t)s_ * Dd + d0 + 4 * j);
            float4 sc = *(const float4*)(sinr + (size_t)s_ * Dd + d0 + 4 * j);
            vv[4*j] = a.x; vv[4*j+1] = a.y; vv[4*j+2] = a.z; vv[4*j+3] = a.w;
            pv[4*j] = p.x; pv[4*j+1] = p.y; pv[4*j+2] = p.z; pv[4*j+3] = p.w;
            cv[4*j] = cc.x; cv[4*j+1] = cc.y; cv[4*j+2] = cc.z; cv[4*j+3] = cc.w;
            sv[4*j] = sc.x; sv[4*j+1] = sc.y; sv[4*j+2] = sc.z; sv[4*j+3] = sc.w;
        }
        __align__(16) u16 o[16];
        #pragma unroll
        for (int i = 0; i < 16; i++)
            o[i] = f2bf(vv[i] * cv[i] + sign * pv[i] * sv[i]);
        u16* la = sA + r * RP + d0;
        *(u16x8*)la = *(const u16x8*)o;
        *(u16x8*)(la + 8) = *((const u16x8*)o + 1);
        if (IS_K && tid < 32) sidx[tid] = idx[blk * 32 + tid];
    }
    __syncthreads();

    int w = tid >> 6, lane = tid & 63, quad = lane >> 4, l15 = lane & 15;
    int rs = (w & 1) * 16, cg = (w >> 1) * 64;
    f32x4 acc[4] = {};
    #pragma unroll
    for (int kb = 0; kb < 4; kb++) {
        bf16x8 a = *(const bf16x8*)(sA + (rs + l15) * RP + kb * 32 + quad * 8);
        #pragma unroll
        for (int nt = 0; nt < 4; nt++) {
            bf16x8 b = *(const bf16x8*)(sB + (cg + nt * 16 + l15) * RP + kb * 32 + quad * 8);
            acc[nt] = __builtin_amdgcn_mfma_f32_16x16x32_bf16(a, b, acc[nt], 0, 0, 0);
        }
    }
    #pragma unroll
    for (int reg = 0; reg < 4; reg++) {
        float m = 0.f;
        #pragma unroll
        for (int nt = 0; nt < 4; nt++) m = fmaxf(m, fabsf(acc[nt][reg]));
        m = fmaxf(m, __shfl_xor(m, 8));
        m = fmaxf(m, __shfl_xor(m, 4));
        m = fmaxf(m, __shfl_xor(m, 2));
        m = fmaxf(m, __shfl_xor(m, 1));
        if (l15 == 0) pamax[rs + quad * 4 + reg][w >> 1] = m;
    }
    __syncthreads();
    #pragma unroll
    for (int reg = 0; reg < 4; reg++) {
        int r = rs + quad * 4 + reg;
        float am = fmaxf(pamax[r][0], pamax[r][1]);
        float scale = fmaxf(am * (1.f / 127.f), 1e-8f);
        float inv = 1.f / scale;
        size_t dro = IS_K ? (size_t)sidx[r] * Dd : (size_t)blk * 4096 + (size_t)r * Dd;
        #pragma unroll
        for (int nt = 0; nt < 4; nt++)
            dstq[dro + cg + nt * 16 + l15] = rintf(acc[nt][reg] * inv);
        if (l15 == 0 && (w >> 1) == 0)
            dsts[IS_K ? sidx[r] : blk * Hn + r] = scale;
    }
}

// ---------------- launch ------------------------------------------------
extern "C" void kernel_launch(void* const* d_in, const int* in_sizes, int n_in,
                              void* d_out, int out_size, void* d_ws, size_t ws_size,
                              hipStream_t stream) {
    (void)in_sizes; (void)n_in; (void)out_size; (void)ws_size;
    const float* x    = (const float*)d_in[0];
    const float* qn   = (const float*)d_in[1];
    const float* qns  = (const float*)d_in[2];
    const float* wqb  = (const float*)d_in[3];
    const float* wqbs = (const float*)d_in[4];
    const float* wk   = (const float*)d_in[5];
    const float* wpj  = (const float*)d_in[6];
    const float* g    = (const float*)d_in[7];
    const float* b    = (const float*)d_in[8];
    const float* cosr = (const float*)d_in[9];
    const float* sinr = (const float*)d_in[10];
    const float* hq   = (const float*)d_in[11];
    const float* hk   = (const float*)d_in[12];
    const float* kc   = (const float*)d_in[13];
    const float* kcs  = (const float*)d_in[14];
    const int*   idx  = (const int*)d_in[15];

    // ws layout
    char* ws = (char*)d_ws;
    size_t o = 0;
    u16* xb  = (u16*)(ws + o); o += (size_t)Mrows * Hdim * 2;   // 33.55 MB
    u16* wt  = (u16*)(ws + o); o += (size_t)NFULL * Hdim * 2;   // 17.83 MB
    u16* hqt = (u16*)(ws + o); o += Dd * Dd * 2;
    u16* hkt = (u16*)(ws + o); o += Dd * Dd * 2;
    float* rmsb  = (float*)(ws + o); o += (size_t)Mrows * 4;
    float* mub   = (float*)(ws + o); o += (size_t)Mrows * 4;
    float* rstdb = (float*)(ws + o); o += (size_t)Mrows * 4;
    float* bdotb = (float*)(ws + o); o += 512;
    float* gdotb = (float*)(ws + o); o += 512;
    float* kpre  = (float*)(ws + o); o += (size_t)Mrows * Dd * 4;  // 4.19 MB

    float* out = (float*)d_out;
    float* oq  = out;                             // [M][4096]
    float* oqs = oq  + (size_t)Mrows * HnD;       // [M][32]
    float* ok  = oqs + (size_t)Mrows * Hn;        // [L][128]
    float* oks = ok  + (size_t)Lc * Dd;           // [L]
    float* ow  = oks + Lc;                        // [M][32]

    stats_cvt<<<Mrows, 256, 0, stream>>>(x, xb, rmsb, mub, rstdb);
    prep_wt<<<dim3(Hdim / 64, NFULL / 64), 256, 0, stream>>>(wqb, qn, qns, wk, g, wpj, wt);
    transpose_h<<<2, 256, 0, stream>>>(hq, hk, hqt, hkt);
    bg_dot<<<Dd, 256, 0, stream>>>(wk, g, b, bdotb, gdotb);
    kw_gemm<<<Mrows / 32, 256, 0, stream>>>(xb, wt, rstdb, mub, bdotb, gdotb, kpre, ow);
    main_gemm<<<dim3(Mrows / 128, 16), 256, 0, stream>>>(
        xb, wt, rmsb, wqbs, hqt, cosr, sinr, oq, oqs);
    copy_cache<<<(Lc * Dd / 8) / 256, 256, 0, stream>>>(kc, kcs, ok, oks);
    post_kernel<1><<<Mrows / 32, 256, 0, stream>>>(kpre, hkt, cosr, sinr, idx, ok, oks);
}

// Round 6
// 457.878 us; speedup vs baseline: 1.2616x; 1.0852x over previous
//
#include <hip/hip_runtime.h>
#include <hip/hip_bf16.h>
#include <stdint.h>

// ---------------- problem constants (from setup_inputs) ----------------
constexpr int Mrows = 8192;   // B*S
constexpr int Hdim  = 2048;   // K of main GEMM
constexpr int Sdim  = 4096;
constexpr int HnD   = 4096;   // Hn*D
constexpr int Hn    = 32;
constexpr int Dd    = 128;
constexpr int Lc    = 16384;
constexpr int NFULL = 4352;   // staged B' rows: 4096 q + 128 k + 32 w + pad

typedef unsigned short u16;
typedef __attribute__((ext_vector_type(8))) short    bf16x8;
typedef __attribute__((ext_vector_type(4))) float    f32x4;
typedef __attribute__((ext_vector_type(8))) unsigned short u16x8;

__device__ __forceinline__ u16 f2bf(float f) {
    union { float f; unsigned int i; } v; v.f = f;
    unsigned int x = v.i;
    return (u16)((x + 0x7fffu + ((x >> 16) & 1u)) >> 16);   // RNE
}
__device__ __forceinline__ void gload_lds16(const void* g, void* l) {
    __builtin_amdgcn_global_load_lds(
        (const __attribute__((address_space(1))) void*)g,
        (__attribute__((address_space(3))) void*)l, 16, 0, 0);
}

// ---------------- 1) fused prep: stats | prep_wt | transpose_h | bg_dot | copy
// block ranges: [0,8192) stats_cvt; [8192,10368) prep_wt; [10368,10376)
// hadamard transpose (8x 64x64 tiles); [10376,10504) bg_dot; [10504,11528)
// copy_cache. One launch replaces 5.
__global__ __launch_bounds__(256) void fused_prep(
    const float* __restrict__ x, u16* __restrict__ xb, float* __restrict__ rms,
    float* __restrict__ mu, float* __restrict__ rstd,
    const float* __restrict__ wqb, const float* __restrict__ qn, const float* __restrict__ qns,
    const float* __restrict__ wk,  const float* __restrict__ g,  const float* __restrict__ wproj,
    u16* __restrict__ wt,
    const float* __restrict__ hq, const float* __restrict__ hk,
    u16* __restrict__ hqt, u16* __restrict__ hkt,
    const float* __restrict__ b,
    float* __restrict__ bdot, float* __restrict__ gdot,
    const float* __restrict__ kc, const float* __restrict__ kcs,
    float* __restrict__ dk, float* __restrict__ dks)
{
    __shared__ u16 utile[64 * 72];
    __shared__ float sred[8];
    int bid = blockIdx.x, t = threadIdx.x;

    if (bid < 8192) {
        // ---- per-row stats + fp32->bf16 copy of x ----
        int r = bid;
        const float4* xr = (const float4*)(x + (size_t)r * Hdim);
        float4 a4 = xr[2 * t], b4 = xr[2 * t + 1];
        float v[8] = {a4.x, a4.y, a4.z, a4.w, b4.x, b4.y, b4.z, b4.w};
        float s = 0.f, ss = 0.f;
        __align__(16) u16 o[8];
        #pragma unroll
        for (int i = 0; i < 8; i++) { s += v[i]; ss += v[i] * v[i]; o[i] = f2bf(v[i]); }
        ((u16x8*)(xb + (size_t)r * Hdim))[t] = *(const u16x8*)o;
        for (int oo = 32; oo > 0; oo >>= 1) { s += __shfl_down(s, oo); ss += __shfl_down(ss, oo); }
        if ((t & 63) == 0) { sred[t >> 6] = s; sred[4 + (t >> 6)] = ss; }
        __syncthreads();
        if (t == 0) {
            float S1 = sred[0] + sred[1] + sred[2] + sred[3];
            float S2 = sred[4] + sred[5] + sred[6] + sred[7];
            float mean = S1 / Hdim, msq = S2 / Hdim;
            rms[r]  = rsqrtf(msq + 1e-6f);
            mu[r]   = mean;
            rstd[r] = rsqrtf(msq - mean * mean + 1e-6f);
        }
    } else if (bid < 10368) {
        // ---- build B'^T = [c1*wqb | g*wk | wproj | 0]^T ----
        int b2 = bid - 8192;
        int k0 = (b2 & 31) * 64, n0 = (b2 >> 5) * 64;
        int lk = t >> 2, lc0 = (t & 3) * 16;
        int k = k0 + lk;
        float c1k = qn[k] * qns[k];
        float gk  = g[k];
        #pragma unroll
        for (int i = 0; i < 16; i++) {
            int n = n0 + lc0 + i;
            float val;
            if (n < 4096)      val = wqb[(size_t)k * HnD + n] * c1k;
            else if (n < 4224) val = wk[k * Dd + (n - 4096)] * gk;
            else if (n < 4256) val = wproj[k * Hn + (n - 4224)];
            else               val = 0.f;
            utile[lk * 72 + lc0 + i] = f2bf(val);
        }
        __syncthreads();
        int ln = t >> 2, lk0 = (t & 3) * 16;
        __align__(16) u16 o[16];
        #pragma unroll
        for (int i = 0; i < 16; i++) o[i] = utile[(lk0 + i) * 72 + ln];
        u16* dst = wt + (size_t)(n0 + ln) * Hdim + k0 + lk0;
        *(u16x8*)dst = *(const u16x8*)o;
        *(u16x8*)(dst + 8) = *((const u16x8*)o + 1);
    } else if (bid < 10376) {
        // ---- hadamard transpose to bf16: 64x64 tiles ----
        int q = bid - 10368;
        int matq = q >> 2, tr = (q >> 1) & 1, tc = q & 1;
        const float* src = matq ? hk : hq;
        u16* dst = matq ? hkt : hqt;
        int r = t >> 2, c0 = (t & 3) * 16;
        #pragma unroll
        for (int i = 0; i < 4; i++) {
            float4 vv = *(const float4*)(src + (size_t)(tr * 64 + r) * Dd + tc * 64 + c0 + 4 * i);
            utile[r * 72 + c0 + 4 * i]     = f2bf(vv.x);
            utile[r * 72 + c0 + 4 * i + 1] = f2bf(vv.y);
            utile[r * 72 + c0 + 4 * i + 2] = f2bf(vv.z);
            utile[r * 72 + c0 + 4 * i + 3] = f2bf(vv.w);
        }
        __syncthreads();
        int n = t >> 2, k0 = (t & 3) * 16;
        __align__(16) u16 o[16];
        #pragma unroll
        for (int i = 0; i < 16; i++) o[i] = utile[(k0 + i) * 72 + n];
        u16* dp = dst + (size_t)(tc * 64 + n) * Dd + tr * 64 + k0;
        *(u16x8*)dp = *(const u16x8*)o;
        *(u16x8*)(dp + 8) = *((const u16x8*)o + 1);
    } else if (bid < 10504) {
        // ---- bdot/gdot ----
        int n = bid - 10376;
        float sb = 0.f, sg = 0.f;
        for (int k = t; k < Hdim; k += 256) {
            float w = wk[k * Dd + n];
            sb += b[k] * w;
            sg += g[k] * w;
        }
        for (int o = 32; o > 0; o >>= 1) { sb += __shfl_down(sb, o); sg += __shfl_down(sg, o); }
        if ((t & 63) == 0) { sred[t >> 6] = sb; sred[4 + (t >> 6)] = sg; }
        __syncthreads();
        if (t == 0) {
            bdot[n] = sred[0] + sred[1] + sred[2] + sred[3];
            gdot[n] = sred[4] + sred[5] + sred[6] + sred[7];
        }
    } else {
        // ---- copy cache defaults into outputs ----
        int gg = (bid - 10504) * 256 + t;
        ((float4*)dk)[2 * gg]     = ((const float4*)kc)[2 * gg];
        ((float4*)dk)[2 * gg + 1] = ((const float4*)kc)[2 * gg + 1];
        if (gg < Lc / 8) {
            ((float4*)dks)[2 * gg]     = ((const float4*)kcs)[2 * gg];
            ((float4*)dks)[2 * gg + 1] = ((const float4*)kcs)[2 * gg + 1];
        }
    }
}

// ---------------- 2) main fused q-GEMM: m201 8-phase template --------------
// BM=BN=256, BK=64, 512 thr = 8 waves (4M x 2N: wave = 64 rows x one 128-col
// head -> in-register RoPE partner nt^4). LDS 128 KiB dbuf; per tile 4 stage
// units {A-K0, A-K1, B-K0, B-K1} of 256 rows x 32 K (2 loads/thread each).
// 8 phases per 2 K-tiles: {ds_read frags || 1 stage unit -> lgkmcnt(0) ->
// 16 MFMA (setprio) -> barrier}; counted vmcnt(6) ONLY at phases 4 & 8
// (3 units in flight; never 0 until the peeled last iter). XOR 16B-slot
// swizzle both-sides (<=2-way, free). Epilogue = fused RoPE+hadamard+quant.
#define RA(bufo, ks, mt) (*(const bf16x8*)(lds + (bufo) * 65536 + (ks) * 16384 + \
    (wr * 64 + (mt) * 16 + l15) * 64 + rsw))
#define RB(bufo, ks, nh, j) (*(const bf16x8*)(lds + (bufo) * 65536 + 32768 + (ks) * 16384 + \
    (wc * 128 + (nh) * 64 + (j) * 16 + l15) * 64 + rsw))
#define SA(tt, ks) do { \
    const u16* gp_ = Ab + (size_t)srow * Hdim + (tt) * 64 + (ks) * 32 + scol; \
    char* dp_ = lds + (((tt) & 1) * 65536) + (ks) * 16384 + wq; \
    gload_lds16(gp_, dp_); \
    gload_lds16(gp_ + (size_t)128 * Hdim, dp_ + 8192); \
} while (0)
#define SB(tt, ks) do { \
    const u16* gp_ = Bb + (size_t)srow * Hdim + (tt) * 64 + (ks) * 32 + scol; \
    char* dp_ = lds + (((tt) & 1) * 65536) + 32768 + (ks) * 16384 + wq; \
    gload_lds16(gp_, dp_); \
    gload_lds16(gp_ + (size_t)128 * Hdim, dp_ + 8192); \
} while (0)
#define VM6 do { asm volatile("s_waitcnt vmcnt(6)" ::: "memory"); __builtin_amdgcn_sched_barrier(0); } while (0)
#define VM0 do { asm volatile("s_waitcnt vmcnt(0)" ::: "memory"); __builtin_amdgcn_sched_barrier(0); } while (0)
#define NOPS ((void)0)
#define PH(bufo, ks, nh, STG, WT) do { \
    if ((nh) == 0) { \
        _Pragma("unroll") for (int mt = 0; mt < 4; mt++) af[mt] = RA(bufo, ks, mt); \
    } \
    _Pragma("unroll") for (int j = 0; j < 4; j++) bfr[j] = RB(bufo, ks, nh, j); \
    STG; \
    asm volatile("s_waitcnt lgkmcnt(0)" ::: "memory"); \
    __builtin_amdgcn_sched_barrier(0); \
    __builtin_amdgcn_s_setprio(1); \
    _Pragma("unroll") for (int mt = 0; mt < 4; mt++) \
        _Pragma("unroll") for (int j = 0; j < 4; j++) \
            acc[mt][(nh) * 4 + j] = __builtin_amdgcn_mfma_f32_16x16x32_bf16( \
                af[mt], bfr[j], acc[mt][(nh) * 4 + j], 0, 0, 0); \
    __builtin_amdgcn_s_setprio(0); \
    WT; \
    __builtin_amdgcn_s_barrier(); \
} while (0)

__global__ __launch_bounds__(512, 1) void main_gemm(
    const u16* __restrict__ A, const u16* __restrict__ Bt,
    const float* __restrict__ rms, const float* __restrict__ qbs,
    const u16* __restrict__ hqt,
    const float* __restrict__ cosr, const float* __restrict__ sinr,
    float* __restrict__ oq, float* __restrict__ oqs)
{
    __shared__ __align__(16) char lds[131072];

    int tid = threadIdx.x;
    int w = tid >> 6, lane = tid & 63, quad = lane >> 4, l15 = lane & 15;
    int wr = w & 3, wc = w >> 2;                 // 4 M-waves x 2 N-waves
    int bm = blockIdx.x, bn = blockIdx.y;
    int brow = bm * 256;
    int rsw = (quad ^ ((l15 >> 1) & 3)) * 16;    // read-side 16B-slot swizzle

    const u16* Ab = A  + (size_t)brow * Hdim;
    const u16* Bb = Bt + (size_t)(bn * 256) * Hdim;

    // staging: unit = 256 rows x 32 K; thread loads rows srow, srow+128
    int srow = tid >> 2;                         // 0..127
    int scol = (((tid & 3) ^ ((srow >> 1) & 3)) * 8);   // pre-swizzled chunk
    int wq = w * 1024;                           // wave-uniform dest part

    bf16x8 af[4], bfr[4];
    f32x4 acc[4][8] = {};

    // prologue: units AK0(0),BK0(0),AK1(0),BK1(0),AK0(1),BK0(1),AK1(1)
    SA(0, 0); SB(0, 0); SA(0, 1); SB(0, 1); SA(1, 0); SB(1, 0); SA(1, 1);
    VM6;                                         // tile 0 fully landed
    __builtin_amdgcn_s_barrier();

    for (int I = 0; I < 15; I++) {
        int t1 = 2 * I + 1, t2 = 2 * I + 2, t3 = 2 * I + 3;
        PH(0, 0, 0, SB(t1, 1), NOPS);            // stage BK1(t+1)
        PH(0, 0, 1, SA(t2, 0), NOPS);            // AK0(t+2)
        PH(0, 1, 0, SB(t2, 0), NOPS);            // BK0(t+2)
        PH(0, 1, 1, SA(t2, 1), VM6);             // AK1(t+2); t+1 complete
        PH(1, 0, 0, SB(t2, 1), NOPS);            // BK1(t+2)
        PH(1, 0, 1, SA(t3, 0), NOPS);            // AK0(t+3)
        PH(1, 1, 0, SB(t3, 0), NOPS);            // BK0(t+3)
        PH(1, 1, 1, SA(t3, 1), VM6);             // AK1(t+3); t+2 K0 complete
    }
    // peeled last iter: t = 30, 31
    PH(0, 0, 0, SB(31, 1), NOPS);                // stage BK1(31) (last unit)
    PH(0, 0, 1, NOPS, NOPS);
    PH(0, 1, 0, NOPS, NOPS);
    PH(0, 1, 1, NOPS, VM0);                      // drain: tile 31 all landed
    PH(1, 0, 0, NOPS, NOPS);
    PH(1, 0, 1, NOPS, NOPS);
    PH(1, 1, 0, NOPS, NOPS);
    PH(1, 1, 1, NOPS, NOPS);

    // -------- fused q epilogue: scale -> RoPE -> P (per-wave LDS, swizzled)
    //          -> hadamard MFMA -> absmax -> quant -> store
    __syncthreads();
    int head = bn * 2 + wc;                      // 0..31
    char* Pw = lds + w * 16384;                  // per-wave [64][256B] region
    float qb[8];
    #pragma unroll
    for (int nt = 0; nt < 8; nt++) qb[nt] = qbs[head * 128 + nt * 16 + l15];
    #pragma unroll
    for (int mt = 0; mt < 4; mt++) {
        float y[8][4];
        #pragma unroll
        for (int reg = 0; reg < 4; reg++) {
            float rv = rms[brow + wr * 64 + mt * 16 + quad * 4 + reg];
            #pragma unroll
            for (int nt = 0; nt < 8; nt++) y[nt][reg] = acc[mt][nt][reg] * rv * qb[nt];
        }
        #pragma unroll
        for (int reg = 0; reg < 4; reg++) {
            int rp = mt * 16 + quad * 4 + reg;          // 0..63 local row
            int s_ = (brow + wr * 64 + rp) & (Sdim - 1);
            const float* cr = cosr + (size_t)s_ * Dd + l15;
            const float* sr = sinr + (size_t)s_ * Dd + l15;
            int sw = (rp & 7) << 4;
            #pragma unroll
            for (int nt = 0; nt < 8; nt++) {
                float c  = cr[nt * 16];
                float sv = sr[nt * 16];
                float sign = (nt < 4) ? -1.f : 1.f;
                float o = y[nt][reg] * c + sign * y[nt ^ 4][reg] * sv;   // fp32 RoPE
                int colb = (nt * 16 + l15) * 2;
                *(u16*)(Pw + rp * 256 + (colb ^ sw)) = f2bf(o);
            }
        }
    }
    __syncthreads();
    #pragma unroll
    for (int mt = 0; mt < 4; mt++) {
        bf16x8 pa[4];
        #pragma unroll
        for (int kb = 0; kb < 4; kb++) {
            int row = mt * 16 + l15;
            pa[kb] = *(const bf16x8*)(Pw + row * 256 + ((kb * 64 + quad * 16) ^ ((row & 7) << 4)));
        }
        f32x4 a2[8] = {};
        #pragma unroll
        for (int nt = 0; nt < 8; nt++) {
            #pragma unroll
            for (int kb = 0; kb < 4; kb++) {
                bf16x8 hb = *(const bf16x8*)(hqt + (size_t)(nt * 16 + l15) * Dd + kb * 32 + quad * 8);
                a2[nt] = __builtin_amdgcn_mfma_f32_16x16x32_bf16(pa[kb], hb, a2[nt], 0, 0, 0);
            }
        }
        #pragma unroll
        for (int reg = 0; reg < 4; reg++) {
            float m = 0.f;
            #pragma unroll
            for (int nt = 0; nt < 8; nt++) m = fmaxf(m, fabsf(a2[nt][reg]));
            m = fmaxf(m, __shfl_xor(m, 8));
            m = fmaxf(m, __shfl_xor(m, 4));
            m = fmaxf(m, __shfl_xor(m, 2));
            m = fmaxf(m, __shfl_xor(m, 1));
            float scale = fmaxf(m * (1.f / 127.f), 1e-8f);
            float inv = 1.f / scale;
            int r = brow + wr * 64 + mt * 16 + quad * 4 + reg;
            float* orow = oq + (size_t)r * HnD + head * 128;
            #pragma unroll
            for (int nt = 0; nt < 8; nt++)
                orow[nt * 16 + l15] = rintf(a2[nt][reg] * inv);
            if (l15 == 0) oqs[(size_t)r * Hn + head] = scale;
        }
    }
}

// ---------------- 3) k_branch: kw-GEMM + LN-affine + RoPE + hadamard + quant
// Block = 32 rows. GEMM over B' cols 4096..4255 (k 128 + w 32), K=2048, BK=64,
// 3-slot counted-vmcnt pipeline. Wave (mh = w&1, ngrp = w>>1) owns rows
// mh*16.. and frag set F = {2g,2g+1,4+2g,5+2g,8+g}: RoPE partner j^2 in-wave.
// Then P bf16 -> hadamard MFMA (hkt from global) -> absmax -> quant -> scatter.
__global__ __launch_bounds__(256) void k_branch(
    const u16* __restrict__ A, const u16* __restrict__ Bt,
    const float* __restrict__ rstd, const float* __restrict__ mu,
    const float* __restrict__ bdot, const float* __restrict__ gdot,
    const u16* __restrict__ hkt,
    const float* __restrict__ cosr, const float* __restrict__ sinr,
    const int* __restrict__ idx,
    float* __restrict__ ok, float* __restrict__ oks, float* __restrict__ wout)
{
    __shared__ __align__(16) char klds[73728];   // 3 slots x (A 4KB + B 20KB)
    __shared__ float pamax[32][2];
    __shared__ int sidx[32];
    int tid = threadIdx.x, w = tid >> 6, lane = tid & 63, quad = lane >> 4, l15 = lane & 15;
    int blk = blockIdx.x;
    int mh = w & 1, ngrp = w >> 1;
    const u16* Ab = A + (size_t)(blk * 32) * Hdim;
    const u16* Bb = Bt + (size_t)4096 * Hdim;
    int F[5];
    F[0] = ngrp * 2; F[1] = ngrp * 2 + 1; F[2] = 4 + ngrp * 2; F[3] = 5 + ngrp * 2; F[4] = 8 + ngrp;
    int ar = tid >> 3, ach = ((tid & 7) ^ (ar & 7)) * 8;   // pre-swizzled A chunk
    int wq1 = w * 1024;

#define KSTG(slotn, st) do { \
    gload_lds16(Ab + (size_t)ar * Hdim + (st) * 64 + ach, klds + (slotn) * 24576 + wq1); \
    _Pragma("unroll") for (int u = 0; u < 5; u++) { \
        int ix = u * 256 + tid; int br = ix >> 3; int bch = ((ix & 7) ^ (br & 7)) * 8; \
        gload_lds16(Bb + (size_t)br * Hdim + (st) * 64 + bch, \
                    klds + (slotn) * 24576 + 4096 + u * 4096 + wq1); \
    } \
} while (0)
#define KRA(slotn, ks) (*(const bf16x8*)(klds + (slotn) * 24576 + \
    (mh * 16 + l15) * 128 + ((((ks) * 4 + quad) ^ (l15 & 7)) * 16)))
#define KRB(slotn, ks, f) (*(const bf16x8*)(klds + (slotn) * 24576 + 4096 + \
    ((f) * 16 + l15) * 128 + ((((ks) * 4 + quad) ^ (l15 & 7)) * 16)))

    f32x4 acc[5] = {};
    KSTG(0, 0); KSTG(1, 1);
    asm volatile("s_waitcnt vmcnt(6)" ::: "memory");
    __builtin_amdgcn_sched_barrier(0);
    __builtin_amdgcn_s_barrier();
    int sl = 0;
    for (int s = 0; s < 32; s++) {
        bf16x8 ka[2], kbf[2][5];
        ka[0] = KRA(sl, 0); ka[1] = KRA(sl, 1);
        #pragma unroll
        for (int j = 0; j < 5; j++) { kbf[0][j] = KRB(sl, 0, F[j]); kbf[1][j] = KRB(sl, 1, F[j]); }
        if (s + 2 < 32) { int ns = sl + 2; if (ns >= 3) ns -= 3; KSTG(ns, s + 2); }
        asm volatile("s_waitcnt lgkmcnt(0)" ::: "memory");
        __builtin_amdgcn_sched_barrier(0);
        __builtin_amdgcn_s_setprio(1);
        #pragma unroll
        for (int ks = 0; ks < 2; ks++)
            #pragma unroll
            for (int j = 0; j < 5; j++)
                acc[j] = __builtin_amdgcn_mfma_f32_16x16x32_bf16(ka[ks], kbf[ks][j], acc[j], 0, 0, 0);
        __builtin_amdgcn_s_setprio(0);
        if (s < 30) { asm volatile("s_waitcnt vmcnt(6)" ::: "memory"); }
        else        { asm volatile("s_waitcnt vmcnt(0)" ::: "memory"); }
        __builtin_amdgcn_sched_barrier(0);
        __builtin_amdgcn_s_barrier();
        sl++; if (sl == 3) sl = 0;
    }

    if (tid < 32) sidx[tid] = idx[blk * 32 + tid];
    __syncthreads();                    // GEMM LDS reads done; overlay P
    u16* sP = (u16*)klds;               // [32][136]
    #pragma unroll
    for (int reg = 0; reg < 4; reg++) {
        int rl = mh * 16 + quad * 4 + reg;
        int r = blk * 32 + rl;
        float sd = rstd[r], m_ = mu[r];
        int s_ = r & (Sdim - 1);
        float v[4];
        #pragma unroll
        for (int j = 0; j < 4; j++) {
            int col = F[j] * 16 + l15;
            v[j] = acc[j][reg] * sd + bdot[col] - sd * m_ * gdot[col];
        }
        #pragma unroll
        for (int j = 0; j < 4; j++) {
            int col = F[j] * 16 + l15;
            float c = cosr[(size_t)s_ * Dd + col], sv = sinr[(size_t)s_ * Dd + col];
            float sign = (j < 2) ? -1.f : 1.f;
            sP[rl * 136 + col] = f2bf(v[j] * c + sign * v[j ^ 2] * sv);   // fp32 RoPE
        }
        wout[(size_t)r * Hn + (F[4] - 8) * 16 + l15] = acc[4][reg];
    }
    __syncthreads();
    f32x4 a2[4] = {};
    #pragma unroll
    for (int kb4 = 0; kb4 < 4; kb4++) {
        bf16x8 pa = *(const bf16x8*)(sP + (mh * 16 + l15) * 136 + kb4 * 32 + quad * 8);
        #pragma unroll
        for (int nt = 0; nt < 4; nt++) {
            bf16x8 hb = *(const bf16x8*)(hkt + (size_t)(ngrp * 64 + nt * 16 + l15) * Dd + kb4 * 32 + quad * 8);
            a2[nt] = __builtin_amdgcn_mfma_f32_16x16x32_bf16(pa, hb, a2[nt], 0, 0, 0);
        }
    }
    #pragma unroll
    for (int reg = 0; reg < 4; reg++) {
        float m = 0.f;
        #pragma unroll
        for (int nt = 0; nt < 4; nt++) m = fmaxf(m, fabsf(a2[nt][reg]));
        m = fmaxf(m, __shfl_xor(m, 8));
        m = fmaxf(m, __shfl_xor(m, 4));
        m = fmaxf(m, __shfl_xor(m, 2));
        m = fmaxf(m, __shfl_xor(m, 1));
        if (l15 == 0) pamax[mh * 16 + quad * 4 + reg][ngrp] = m;
    }
    __syncthreads();
    #pragma unroll
    for (int reg = 0; reg < 4; reg++) {
        int rl = mh * 16 + quad * 4 + reg;
        float am = fmaxf(pamax[rl][0], pamax[rl][1]);
        float scale = fmaxf(am * (1.f / 127.f), 1e-8f);
        float inv = 1.f / scale;
        size_t dro = (size_t)sidx[rl] * Dd;
        #pragma unroll
        for (int nt = 0; nt < 4; nt++)
            ok[dro + ngrp * 64 + nt * 16 + l15] = rintf(a2[nt][reg] * inv);
        if (l15 == 0 && ngrp == 0) oks[sidx[rl]] = scale;
    }
}

// ---------------- launch ------------------------------------------------
extern "C" void kernel_launch(void* const* d_in, const int* in_sizes, int n_in,
                              void* d_out, int out_size, void* d_ws, size_t ws_size,
                              hipStream_t stream) {
    (void)in_sizes; (void)n_in; (void)out_size; (void)ws_size;
    const float* x    = (const float*)d_in[0];
    const float* qn   = (const float*)d_in[1];
    const float* qns  = (const float*)d_in[2];
    const float* wqb  = (const float*)d_in[3];
    const float* wqbs = (const float*)d_in[4];
    const float* wk   = (const float*)d_in[5];
    const float* wpj  = (const float*)d_in[6];
    const float* g    = (const float*)d_in[7];
    const float* b    = (const float*)d_in[8];
    const float* cosr = (const float*)d_in[9];
    const float* sinr = (const float*)d_in[10];
    const float* hq   = (const float*)d_in[11];
    const float* hk   = (const float*)d_in[12];
    const float* kc   = (const float*)d_in[13];
    const float* kcs  = (const float*)d_in[14];
    const int*   idx  = (const int*)d_in[15];

    // ws layout
    char* ws = (char*)d_ws;
    size_t o = 0;
    u16* xb  = (u16*)(ws + o); o += (size_t)Mrows * Hdim * 2;   // 33.55 MB
    u16* wt  = (u16*)(ws + o); o += (size_t)NFULL * Hdim * 2;   // 17.83 MB
    u16* hqt = (u16*)(ws + o); o += Dd * Dd * 2;
    u16* hkt = (u16*)(ws + o); o += Dd * Dd * 2;
    float* rmsb  = (float*)(ws + o); o += (size_t)Mrows * 4;
    float* mub   = (float*)(ws + o); o += (size_t)Mrows * 4;
    float* rstdb = (float*)(ws + o); o += (size_t)Mrows * 4;
    float* bdotb = (float*)(ws + o); o += 512;
    float* gdotb = (float*)(ws + o); o += 512;

    float* out = (float*)d_out;
    float* oq  = out;                             // [M][4096]
    float* oqs = oq  + (size_t)Mrows * HnD;       // [M][32]
    float* ok  = oqs + (size_t)Mrows * Hn;        // [L][128]
    float* oks = ok  + (size_t)Lc * Dd;           // [L]
    float* ow  = oks + Lc;                        // [M][32]

    fused_prep<<<11528, 256, 0, stream>>>(
        x, xb, rmsb, mub, rstdb, wqb, qn, qns, wk, g, wpj, wt,
        hq, hk, hqt, hkt, b, bdotb, gdotb, kc, kcs, ok, oks);
    main_gemm<<<dim3(Mrows / 256, 16), 512, 0, stream>>>(
        xb, wt, rmsb, wqbs, hqt, cosr, sinr, oq, oqs);
    k_branch<<<Mrows / 32, 256, 0, stream>>>(
        xb, wt, rstdb, mub, bdotb, gdotb, hkt, cosr, sinr, idx, ok, oks, ow);
}

// Round 7
// 453.004 us; speedup vs baseline: 1.2751x; 1.0108x over previous
//
#include <hip/hip_runtime.h>
#include <hip/hip_bf16.h>
#include <stdint.h>

// ---------------- problem constants (from setup_inputs) ----------------
constexpr int Mrows = 8192;   // B*S
constexpr int Hdim  = 2048;   // K of main GEMM
constexpr int Sdim  = 4096;
constexpr int HnD   = 4096;   // Hn*D
constexpr int Hn    = 32;
constexpr int Dd    = 128;
constexpr int Lc    = 16384;
constexpr int NFULL = 4352;   // staged B' rows: 4096 q + 128 k + 32 w + pad

typedef unsigned short u16;
typedef __attribute__((ext_vector_type(8))) short    bf16x8;
typedef __attribute__((ext_vector_type(4))) float    f32x4;
typedef __attribute__((ext_vector_type(8))) unsigned short u16x8;

__device__ __forceinline__ u16 f2bf(float f) {
    union { float f; unsigned int i; } v; v.f = f;
    unsigned int x = v.i;
    return (u16)((x + 0x7fffu + ((x >> 16) & 1u)) >> 16);   // RNE
}
__device__ __forceinline__ void gload_lds16(const void* g, void* l) {
    __builtin_amdgcn_global_load_lds(
        (const __attribute__((address_space(1))) void*)g,
        (__attribute__((address_space(3))) void*)l, 16, 0, 0);
}

// ---------------- 1) fused prep: stats | prep_wt | transpose_h | bg_dot | copy
__global__ __launch_bounds__(256) void fused_prep(
    const float* __restrict__ x, u16* __restrict__ xb, float* __restrict__ rms,
    float* __restrict__ mu, float* __restrict__ rstd,
    const float* __restrict__ wqb, const float* __restrict__ qn, const float* __restrict__ qns,
    const float* __restrict__ wk,  const float* __restrict__ g,  const float* __restrict__ wproj,
    u16* __restrict__ wt,
    const float* __restrict__ hq, const float* __restrict__ hk,
    u16* __restrict__ hqt, u16* __restrict__ hkt,
    const float* __restrict__ b,
    float* __restrict__ bdot, float* __restrict__ gdot,
    const float* __restrict__ kc, const float* __restrict__ kcs,
    float* __restrict__ dk, float* __restrict__ dks)
{
    __shared__ u16 utile[64 * 72];
    __shared__ float sred[8];
    int bid = blockIdx.x, t = threadIdx.x;

    if (bid < 8192) {
        // ---- per-row stats + fp32->bf16 copy of x ----
        int r = bid;
        const float4* xr = (const float4*)(x + (size_t)r * Hdim);
        float4 a4 = xr[2 * t], b4 = xr[2 * t + 1];
        float v[8] = {a4.x, a4.y, a4.z, a4.w, b4.x, b4.y, b4.z, b4.w};
        float s = 0.f, ss = 0.f;
        __align__(16) u16 o[8];
        #pragma unroll
        for (int i = 0; i < 8; i++) { s += v[i]; ss += v[i] * v[i]; o[i] = f2bf(v[i]); }
        ((u16x8*)(xb + (size_t)r * Hdim))[t] = *(const u16x8*)o;
        for (int oo = 32; oo > 0; oo >>= 1) { s += __shfl_down(s, oo); ss += __shfl_down(ss, oo); }
        if ((t & 63) == 0) { sred[t >> 6] = s; sred[4 + (t >> 6)] = ss; }
        __syncthreads();
        if (t == 0) {
            float S1 = sred[0] + sred[1] + sred[2] + sred[3];
            float S2 = sred[4] + sred[5] + sred[6] + sred[7];
            float mean = S1 / Hdim, msq = S2 / Hdim;
            rms[r]  = rsqrtf(msq + 1e-6f);
            mu[r]   = mean;
            rstd[r] = rsqrtf(msq - mean * mean + 1e-6f);
        }
    } else if (bid < 10368) {
        // ---- build B'^T = [c1*wqb | g*wk | wproj | 0]^T ----
        int b2 = bid - 8192;
        int k0 = (b2 & 31) * 64, n0 = (b2 >> 5) * 64;
        int lk = t >> 2, lc0 = (t & 3) * 16;
        int k = k0 + lk;
        float c1k = qn[k] * qns[k];
        float gk  = g[k];
        #pragma unroll
        for (int i = 0; i < 16; i++) {
            int n = n0 + lc0 + i;
            float val;
            if (n < 4096)      val = wqb[(size_t)k * HnD + n] * c1k;
            else if (n < 4224) val = wk[k * Dd + (n - 4096)] * gk;
            else if (n < 4256) val = wproj[k * Hn + (n - 4224)];
            else               val = 0.f;
            utile[lk * 72 + lc0 + i] = f2bf(val);
        }
        __syncthreads();
        int ln = t >> 2, lk0 = (t & 3) * 16;
        __align__(16) u16 o[16];
        #pragma unroll
        for (int i = 0; i < 16; i++) o[i] = utile[(lk0 + i) * 72 + ln];
        u16* dst = wt + (size_t)(n0 + ln) * Hdim + k0 + lk0;
        *(u16x8*)dst = *(const u16x8*)o;
        *(u16x8*)(dst + 8) = *((const u16x8*)o + 1);
    } else if (bid < 10376) {
        // ---- hadamard transpose to bf16: 64x64 tiles ----
        int q = bid - 10368;
        int matq = q >> 2, tr = (q >> 1) & 1, tc = q & 1;
        const float* src = matq ? hk : hq;
        u16* dst = matq ? hkt : hqt;
        int r = t >> 2, c0 = (t & 3) * 16;
        #pragma unroll
        for (int i = 0; i < 4; i++) {
            float4 vv = *(const float4*)(src + (size_t)(tr * 64 + r) * Dd + tc * 64 + c0 + 4 * i);
            utile[r * 72 + c0 + 4 * i]     = f2bf(vv.x);
            utile[r * 72 + c0 + 4 * i + 1] = f2bf(vv.y);
            utile[r * 72 + c0 + 4 * i + 2] = f2bf(vv.z);
            utile[r * 72 + c0 + 4 * i + 3] = f2bf(vv.w);
        }
        __syncthreads();
        int n = t >> 2, k0 = (t & 3) * 16;
        __align__(16) u16 o[16];
        #pragma unroll
        for (int i = 0; i < 16; i++) o[i] = utile[(k0 + i) * 72 + n];
        u16* dp = dst + (size_t)(tc * 64 + n) * Dd + tr * 64 + k0;
        *(u16x8*)dp = *(const u16x8*)o;
        *(u16x8*)(dp + 8) = *((const u16x8*)o + 1);
    } else if (bid < 10504) {
        // ---- bdot/gdot ----
        int n = bid - 10376;
        float sb = 0.f, sg = 0.f;
        for (int k = t; k < Hdim; k += 256) {
            float w = wk[k * Dd + n];
            sb += b[k] * w;
            sg += g[k] * w;
        }
        for (int o = 32; o > 0; o >>= 1) { sb += __shfl_down(sb, o); sg += __shfl_down(sg, o); }
        if ((t & 63) == 0) { sred[t >> 6] = sb; sred[4 + (t >> 6)] = sg; }
        __syncthreads();
        if (t == 0) {
            bdot[n] = sred[0] + sred[1] + sred[2] + sred[3];
            gdot[n] = sred[4] + sred[5] + sred[6] + sred[7];
        }
    } else {
        // ---- copy cache defaults into outputs ----
        int gg = (bid - 10504) * 256 + t;
        ((float4*)dk)[2 * gg]     = ((const float4*)kc)[2 * gg];
        ((float4*)dk)[2 * gg + 1] = ((const float4*)kc)[2 * gg + 1];
        if (gg < Lc / 8) {
            ((float4*)dks)[2 * gg]     = ((const float4*)kcs)[2 * gg];
            ((float4*)dks)[2 * gg + 1] = ((const float4*)kcs)[2 * gg + 1];
        }
    }
}

// ---------------- 2) main fused q-GEMM: 2-phase/tile counted-vmcnt ---------
// BM=BN=256, BK=64, 512 thr = 8 waves (4M x 2N: wave = 64 rows x one 128-col
// head -> in-register RoPE partner nt^4). LDS 128 KiB dbuf; regions per buf:
// AK0|AK1|BK0|BK1, each 256 rows x 32 K (16 KB). Per phase: read ALL 12 frags
// for one 32-K half (4 A + 8 B b128), issue one A+B stage-pair, then a
// 32-MFMA cluster with NO forced lgkmcnt (compiler emits fine-grained
// lgkmcnt(N) so the first MFMA starts when its own operands land — forcing
// lgkmcnt(0) was R6's ~1200 cyc/phase overhead), setprio around the cluster,
// counted vmcnt(8) at phase end (8 newest loads = 2 pending stage-pairs;
// the pair needed next phase was issued 2 phases (~3000 cyc) earlier).
// Region re-stage only in the phase after its last read (barrier-separated).
// Barriers: 2/tile (was 4). Accumulation order unchanged (bit-identical).
#define RA(bufo, ks, mt) (*(const bf16x8*)(lds + (bufo) * 65536 + (ks) * 16384 + \
    (wr * 64 + (mt) * 16 + l15) * 64 + rsw))
#define RB(bufo, ks, j) (*(const bf16x8*)(lds + (bufo) * 65536 + 32768 + (ks) * 16384 + \
    (wc * 128 + (j) * 16 + l15) * 64 + rsw))
#define SA(tt, ks) do { \
    const u16* gp_ = Ab + (size_t)srow * Hdim + (tt) * 64 + (ks) * 32 + scol; \
    char* dp_ = lds + (((tt) & 1) * 65536) + (ks) * 16384 + wq; \
    gload_lds16(gp_, dp_); \
    gload_lds16(gp_ + (size_t)128 * Hdim, dp_ + 8192); \
} while (0)
#define SB(tt, ks) do { \
    const u16* gp_ = Bb + (size_t)srow * Hdim + (tt) * 64 + (ks) * 32 + scol; \
    char* dp_ = lds + (((tt) & 1) * 65536) + 32768 + (ks) * 16384 + wq; \
    gload_lds16(gp_, dp_); \
    gload_lds16(gp_ + (size_t)128 * Hdim, dp_ + 8192); \
} while (0)
#define VM8 asm volatile("s_waitcnt vmcnt(8)" ::: "memory")
#define VM4 asm volatile("s_waitcnt vmcnt(4)" ::: "memory")
#define VM0 asm volatile("s_waitcnt vmcnt(0)" ::: "memory")
#define NOPS ((void)0)
#define PH2(bufo, ks, STG, WT) do { \
    bf16x8 af[4], bq[8]; \
    _Pragma("unroll") for (int mt = 0; mt < 4; mt++) af[mt] = RA(bufo, ks, mt); \
    _Pragma("unroll") for (int j = 0; j < 8; j++) bq[j] = RB(bufo, ks, j); \
    STG; \
    __builtin_amdgcn_s_setprio(1); \
    _Pragma("unroll") for (int mt = 0; mt < 4; mt++) \
        _Pragma("unroll") for (int j = 0; j < 8; j++) \
            acc[mt][j] = __builtin_amdgcn_mfma_f32_16x16x32_bf16( \
                af[mt], bq[j], acc[mt][j], 0, 0, 0); \
    __builtin_amdgcn_s_setprio(0); \
    WT; \
    __builtin_amdgcn_s_barrier(); \
} while (0)

__global__ __launch_bounds__(512, 1) void main_gemm(
    const u16* __restrict__ A, const u16* __restrict__ Bt,
    const float* __restrict__ rms, const float* __restrict__ qbs,
    const u16* __restrict__ hqt,
    const float* __restrict__ cosr, const float* __restrict__ sinr,
    float* __restrict__ oq, float* __restrict__ oqs)
{
    __shared__ __align__(16) char lds[131072];

    int tid = threadIdx.x;
    int w = tid >> 6, lane = tid & 63, quad = lane >> 4, l15 = lane & 15;
    int wr = w & 3, wc = w >> 2;                 // 4 M-waves x 2 N-waves
    int bm = blockIdx.x, bn = blockIdx.y;
    int brow = bm * 256;
    int rsw = (quad ^ ((l15 >> 1) & 3)) * 16;    // read-side 16B-slot swizzle

    const u16* Ab = A  + (size_t)brow * Hdim;
    const u16* Bb = Bt + (size_t)(bn * 256) * Hdim;

    // staging: unit = 256 rows x 32 K; thread loads rows srow, srow+128
    int srow = tid >> 2;                         // 0..127
    int scol = (((tid & 3) ^ ((srow >> 1) & 3)) * 8);   // pre-swizzled chunk
    int wq = w * 1024;                           // wave-uniform dest part

    f32x4 acc[4][8] = {};

    // prologue: AK0/BK0(0), AK1/BK1(0), AK0/BK0(1)  (12 loads/thread)
    SA(0, 0); SB(0, 0); SA(0, 1); SB(0, 1); SA(1, 0); SB(1, 0);
    VM8;                                         // tile-0 kk0 landed
    __builtin_amdgcn_s_barrier();

    // schedule: P0(t) stages AK1/BK1(t+1); P1(t) stages AK0/BK0(t+2)
    #pragma unroll 1
    for (int I = 0; I < 15; I++) {
        int t0 = 2 * I, t1 = 2 * I + 1;
        PH2(0, 0, SA(t0 + 1, 1); SB(t0 + 1, 1), VM8);
        PH2(0, 1, SA(t0 + 2, 0); SB(t0 + 2, 0), VM8);
        PH2(1, 0, SA(t1 + 1, 1); SB(t1 + 1, 1), VM8);
        PH2(1, 1, SA(t1 + 2, 0); SB(t1 + 2, 0), VM8);
    }
    // peeled: t=30 (buf0), t=31 (buf1)
    PH2(0, 0, SA(31, 1); SB(31, 1), VM8);
    PH2(0, 1, NOPS, VM4);
    PH2(1, 0, NOPS, VM0);
    PH2(1, 1, NOPS, NOPS);

    // -------- fused q epilogue: scale -> RoPE -> P (per-wave LDS, swizzled)
    //          -> hadamard MFMA -> absmax -> quant -> store
    __syncthreads();
    int head = bn * 2 + wc;                      // 0..31
    char* Pw = lds + w * 16384;                  // per-wave [64][256B] region
    float qb[8];
    #pragma unroll
    for (int nt = 0; nt < 8; nt++) qb[nt] = qbs[head * 128 + nt * 16 + l15];
    #pragma unroll
    for (int mt = 0; mt < 4; mt++) {
        float y[8][4];
        #pragma unroll
        for (int reg = 0; reg < 4; reg++) {
            float rv = rms[brow + wr * 64 + mt * 16 + quad * 4 + reg];
            #pragma unroll
            for (int nt = 0; nt < 8; nt++) y[nt][reg] = acc[mt][nt][reg] * rv * qb[nt];
        }
        #pragma unroll
        for (int reg = 0; reg < 4; reg++) {
            int rp = mt * 16 + quad * 4 + reg;          // 0..63 local row
            int s_ = (brow + wr * 64 + rp) & (Sdim - 1);
            const float* cr = cosr + (size_t)s_ * Dd + l15;
            const float* sr = sinr + (size_t)s_ * Dd + l15;
            int sw = (rp & 7) << 4;
            #pragma unroll
            for (int nt = 0; nt < 8; nt++) {
                float c  = cr[nt * 16];
                float sv = sr[nt * 16];
                float sign = (nt < 4) ? -1.f : 1.f;
                float o = y[nt][reg] * c + sign * y[nt ^ 4][reg] * sv;   // fp32 RoPE
                int colb = (nt * 16 + l15) * 2;
                *(u16*)(Pw + rp * 256 + (colb ^ sw)) = f2bf(o);
            }
        }
    }
    __syncthreads();
    #pragma unroll
    for (int mt = 0; mt < 4; mt++) {
        bf16x8 pa[4];
        #pragma unroll
        for (int kb = 0; kb < 4; kb++) {
            int row = mt * 16 + l15;
            pa[kb] = *(const bf16x8*)(Pw + row * 256 + ((kb * 64 + quad * 16) ^ ((row & 7) << 4)));
        }
        f32x4 a2[8] = {};
        #pragma unroll
        for (int nt = 0; nt < 8; nt++) {
            #pragma unroll
            for (int kb = 0; kb < 4; kb++) {
                bf16x8 hb = *(const bf16x8*)(hqt + (size_t)(nt * 16 + l15) * Dd + kb * 32 + quad * 8);
                a2[nt] = __builtin_amdgcn_mfma_f32_16x16x32_bf16(pa[kb], hb, a2[nt], 0, 0, 0);
            }
        }
        #pragma unroll
        for (int reg = 0; reg < 4; reg++) {
            float m = 0.f;
            #pragma unroll
            for (int nt = 0; nt < 8; nt++) m = fmaxf(m, fabsf(a2[nt][reg]));
            m = fmaxf(m, __shfl_xor(m, 8));
            m = fmaxf(m, __shfl_xor(m, 4));
            m = fmaxf(m, __shfl_xor(m, 2));
            m = fmaxf(m, __shfl_xor(m, 1));
            float scale = fmaxf(m * (1.f / 127.f), 1e-8f);
            float inv = 1.f / scale;
            int r = brow + wr * 64 + mt * 16 + quad * 4 + reg;
            float* orow = oq + (size_t)r * HnD + head * 128;
            #pragma unroll
            for (int nt = 0; nt < 8; nt++)
                orow[nt * 16 + l15] = rintf(a2[nt][reg] * inv);
            if (l15 == 0) oqs[(size_t)r * Hn + head] = scale;
        }
    }
}

// ---------------- 3) k_branch: kw-GEMM + LN-affine + RoPE + hadamard + quant
__global__ __launch_bounds__(256) void k_branch(
    const u16* __restrict__ A, const u16* __restrict__ Bt,
    const float* __restrict__ rstd, const float* __restrict__ mu,
    const float* __restrict__ bdot, const float* __restrict__ gdot,
    const u16* __restrict__ hkt,
    const float* __restrict__ cosr, const float* __restrict__ sinr,
    const int* __restrict__ idx,
    float* __restrict__ ok, float* __restrict__ oks, float* __restrict__ wout)
{
    __shared__ __align__(16) char klds[73728];   // 3 slots x (A 4KB + B 20KB)
    __shared__ float pamax[32][2];
    __shared__ int sidx[32];
    int tid = threadIdx.x, w = tid >> 6, lane = tid & 63, quad = lane >> 4, l15 = lane & 15;
    int blk = blockIdx.x;
    int mh = w & 1, ngrp = w >> 1;
    const u16* Ab = A + (size_t)(blk * 32) * Hdim;
    const u16* Bb = Bt + (size_t)4096 * Hdim;
    int F[5];
    F[0] = ngrp * 2; F[1] = ngrp * 2 + 1; F[2] = 4 + ngrp * 2; F[3] = 5 + ngrp * 2; F[4] = 8 + ngrp;
    int ar = tid >> 3, ach = ((tid & 7) ^ (ar & 7)) * 8;   // pre-swizzled A chunk
    int wq1 = w * 1024;

#define KSTG(slotn, st) do { \
    gload_lds16(Ab + (size_t)ar * Hdim + (st) * 64 + ach, klds + (slotn) * 24576 + wq1); \
    _Pragma("unroll") for (int u = 0; u < 5; u++) { \
        int ix = u * 256 + tid; int br = ix >> 3; int bch = ((ix & 7) ^ (br & 7)) * 8; \
        gload_lds16(Bb + (size_t)br * Hdim + (st) * 64 + bch, \
                    klds + (slotn) * 24576 + 4096 + u * 4096 + wq1); \
    } \
} while (0)
#define KRA(slotn, ks) (*(const bf16x8*)(klds + (slotn) * 24576 + \
    (mh * 16 + l15) * 128 + ((((ks) * 4 + quad) ^ (l15 & 7)) * 16)))
#define KRB(slotn, ks, f) (*(const bf16x8*)(klds + (slotn) * 24576 + 4096 + \
    ((f) * 16 + l15) * 128 + ((((ks) * 4 + quad) ^ (l15 & 7)) * 16)))

    f32x4 acc[5] = {};
    KSTG(0, 0); KSTG(1, 1);
    asm volatile("s_waitcnt vmcnt(6)" ::: "memory");
    __builtin_amdgcn_s_barrier();
    int sl = 0;
    for (int s = 0; s < 32; s++) {
        bf16x8 ka[2], kbf[2][5];
        ka[0] = KRA(sl, 0); ka[1] = KRA(sl, 1);
        #pragma unroll
        for (int j = 0; j < 5; j++) { kbf[0][j] = KRB(sl, 0, F[j]); kbf[1][j] = KRB(sl, 1, F[j]); }
        if (s + 2 < 32) { int ns = sl + 2; if (ns >= 3) ns -= 3; KSTG(ns, s + 2); }
        __builtin_amdgcn_s_setprio(1);
        #pragma unroll
        for (int ks = 0; ks < 2; ks++)
            #pragma unroll
            for (int j = 0; j < 5; j++)
                acc[j] = __builtin_amdgcn_mfma_f32_16x16x32_bf16(ka[ks], kbf[ks][j], acc[j], 0, 0, 0);
        __builtin_amdgcn_s_setprio(0);
        if (s < 30) { asm volatile("s_waitcnt vmcnt(6)" ::: "memory"); }
        else        { asm volatile("s_waitcnt vmcnt(0)" ::: "memory"); }
        __builtin_amdgcn_s_barrier();
        sl++; if (sl == 3) sl = 0;
    }

    if (tid < 32) sidx[tid] = idx[blk * 32 + tid];
    __syncthreads();                    // GEMM LDS reads done; overlay P
    u16* sP = (u16*)klds;               // [32][136]
    #pragma unroll
    for (int reg = 0; reg < 4; reg++) {
        int rl = mh * 16 + quad * 4 + reg;
        int r = blk * 32 + rl;
        float sd = rstd[r], m_ = mu[r];
        int s_ = r & (Sdim - 1);
        float v[4];
        #pragma unroll
        for (int j = 0; j < 4; j++) {
            int col = F[j] * 16 + l15;
            v[j] = acc[j][reg] * sd + bdot[col] - sd * m_ * gdot[col];
        }
        #pragma unroll
        for (int j = 0; j < 4; j++) {
            int col = F[j] * 16 + l15;
            float c = cosr[(size_t)s_ * Dd + col], sv = sinr[(size_t)s_ * Dd + col];
            float sign = (j < 2) ? -1.f : 1.f;
            sP[rl * 136 + col] = f2bf(v[j] * c + sign * v[j ^ 2] * sv);   // fp32 RoPE
        }
        wout[(size_t)r * Hn + (F[4] - 8) * 16 + l15] = acc[4][reg];
    }
    __syncthreads();
    f32x4 a2[4] = {};
    #pragma unroll
    for (int kb4 = 0; kb4 < 4; kb4++) {
        bf16x8 pa = *(const bf16x8*)(sP + (mh * 16 + l15) * 136 + kb4 * 32 + quad * 8);
        #pragma unroll
        for (int nt = 0; nt < 4; nt++) {
            bf16x8 hb = *(const bf16x8*)(hkt + (size_t)(ngrp * 64 + nt * 16 + l15) * Dd + kb4 * 32 + quad * 8);
            a2[nt] = __builtin_amdgcn_mfma_f32_16x16x32_bf16(pa, hb, a2[nt], 0, 0, 0);
        }
    }
    #pragma unroll
    for (int reg = 0; reg < 4; reg++) {
        float m = 0.f;
        #pragma unroll
        for (int nt = 0; nt < 4; nt++) m = fmaxf(m, fabsf(a2[nt][reg]));
        m = fmaxf(m, __shfl_xor(m, 8));
        m = fmaxf(m, __shfl_xor(m, 4));
        m = fmaxf(m, __shfl_xor(m, 2));
        m = fmaxf(m, __shfl_xor(m, 1));
        if (l15 == 0) pamax[mh * 16 + quad * 4 + reg][ngrp] = m;
    }
    __syncthreads();
    #pragma unroll
    for (int reg = 0; reg < 4; reg++) {
        int rl = mh * 16 + quad * 4 + reg;
        float am = fmaxf(pamax[rl][0], pamax[rl][1]);
        float scale = fmaxf(am * (1.f / 127.f), 1e-8f);
        float inv = 1.f / scale;
        size_t dro = (size_t)sidx[rl] * Dd;
        #pragma unroll
        for (int nt = 0; nt < 4; nt++)
            ok[dro + ngrp * 64 + nt * 16 + l15] = rintf(a2[nt][reg] * inv);
        if (l15 == 0 && ngrp == 0) oks[sidx[rl]] = scale;
    }
}

// ---------------- launch ------------------------------------------------
extern "C" void kernel_launch(void* const* d_in, const int* in_sizes, int n_in,
                              void* d_out, int out_size, void* d_ws, size_t ws_size,
                              hipStream_t stream) {
    (void)in_sizes; (void)n_in; (void)out_size; (void)ws_size;
    const float* x    = (const float*)d_in[0];
    const float* qn   = (const float*)d_in[1];
    const float* qns  = (const float*)d_in[2];
    const float* wqb  = (const float*)d_in[3];
    const float* wqbs = (const float*)d_in[4];
    const float* wk   = (const float*)d_in[5];
    const float* wpj  = (const float*)d_in[6];
    const float* g    = (const float*)d_in[7];
    const float* b    = (const float*)d_in[8];
    const float* cosr = (const float*)d_in[9];
    const float* sinr = (const float*)d_in[10];
    const float* hq   = (const float*)d_in[11];
    const float* hk   = (const float*)d_in[12];
    const float* kc   = (const float*)d_in[13];
    const float* kcs  = (const float*)d_in[14];
    const int*   idx  = (const int*)d_in[15];

    // ws layout
    char* ws = (char*)d_ws;
    size_t o = 0;
    u16* xb  = (u16*)(ws + o); o += (size_t)Mrows * Hdim * 2;   // 33.55 MB
    u16* wt  = (u16*)(ws + o); o += (size_t)NFULL * Hdim * 2;   // 17.83 MB
    u16* hqt = (u16*)(ws + o); o += Dd * Dd * 2;
    u16* hkt = (u16*)(ws + o); o += Dd * Dd * 2;
    float* rmsb  = (float*)(ws + o); o += (size_t)Mrows * 4;
    float* mub   = (float*)(ws + o); o += (size_t)Mrows * 4;
    float* rstdb = (float*)(ws + o); o += (size_t)Mrows * 4;
    float* bdotb = (float*)(ws + o); o += 512;
    float* gdotb = (float*)(ws + o); o += 512;

    float* out = (float*)d_out;
    float* oq  = out;                             // [M][4096]
    float* oqs = oq  + (size_t)Mrows * HnD;       // [M][32]
    float* ok  = oqs + (size_t)Mrows * Hn;        // [L][128]
    float* oks = ok  + (size_t)Lc * Dd;           // [L]
    float* ow  = oks + Lc;                        // [M][32]

    fused_prep<<<11528, 256, 0, stream>>>(
        x, xb, rmsb, mub, rstdb, wqb, qn, qns, wk, g, wpj, wt,
        hq, hk, hqt, hkt, b, bdotb, gdotb, kc, kcs, ok, oks);
    main_gemm<<<dim3(Mrows / 256, 16), 512, 0, stream>>>(
        xb, wt, rmsb, wqbs, hqt, cosr, sinr, oq, oqs);
    k_branch<<<Mrows / 32, 256, 0, stream>>>(
        xb, wt, rstdb, mub, bdotb, gdotb, hkt, cosr, sinr, idx, ok, oks, ow);
}